// Round 2
// baseline (4965.718 us; speedup 1.0000x reference)
//
#include <hip/hip_runtime.h>
#include <hip/hip_bf16.h>

// ---------------------------------------------------------------------------
// Hetero-GCN (3 node types, 9 relations), 2 GraphConv layers + classifier.
// Round 2:
//  - CSR build rewritten with LDS-privatized histograms (NO global atomics);
//    shfl-based scan (2 barriers/tile instead of 16).
//  - Aggregation fused with the per-relation GEMM: gather normalized rows
//    straight into the LDS A-tile, GEMM reads it in place. Removes the
//    920 MB Abuf round-trip.
// All fp32.
// ---------------------------------------------------------------------------

#define NN 50000
#define EE 400000
#define NRANGE 4
#define RANGE 12500   // NN / NRANGE

// REL = [(0,2),(1,2),(1,0),(0,0),(2,1),(2,0),(0,0),(2,2),(1,1)]
__device__ __constant__ int d_rel_of_type[3][4] = {
    {2, 3, 5, 6},   // dst type 0
    {4, 8, -1, -1}, // dst type 1
    {0, 1, 7, -1},  // dst type 2
};

// ---------------- degree histogram (LDS-privatized, no global atomics) ------
// grid: 9 rel x 4 ranges x {src,dst} = 72 blocks
__global__ __launch_bounds__(256) void k_hist(const int* __restrict__ edges,
                                              int* __restrict__ deg_s,
                                              int* __restrict__ deg_d) {
    __shared__ int bins[RANGE];
    int bid = blockIdx.x;
    int r = bid >> 3;
    int p = (bid >> 1) & 3;
    int sd = bid & 1;
    int base = p * RANGE;
    int tid = threadIdx.x;
    for (int i = tid; i < RANGE; i += 256) bins[i] = 0;
    __syncthreads();
    const int* ea = edges + (size_t)r * 2 * EE + (size_t)sd * EE;
    for (int e = tid; e < EE; e += 256) {
        int idx = ea[e] - base;
        if ((unsigned)idx < (unsigned)RANGE) atomicAdd(&bins[idx], 1);
    }
    __syncthreads();
    int* dego = (sd == 0 ? deg_s : deg_d) + r * NN + base;
    for (int i = tid; i < RANGE; i += 256) dego[i] = bins[i];
}

__global__ void k_norms(const int* __restrict__ deg_s, const int* __restrict__ deg_d,
                        float* __restrict__ ns, float* __restrict__ nd) {
    int i = blockIdx.x * blockDim.x + threadIdx.x;
    if (i >= 9 * NN) return;
    int a = deg_s[i];
    int b = deg_d[i];
    ns[i] = (a > 0) ? rsqrtf((float)a) : 0.f;
    nd[i] = (b > 0) ? rsqrtf((float)b) : 0.f;
}

// ---------------- exclusive scan of in-degrees -> CSR offsets ---------------
// 9 blocks (one per relation); shfl wave scan, 2 barriers per 256-tile
__global__ __launch_bounds__(256) void k_offsets(const int* __restrict__ deg_d,
                                                 int* __restrict__ off) {
    __shared__ int wsum[4];
    __shared__ int s_carry;
    int r = blockIdx.x;
    const int* c = deg_d + r * NN;
    int* o = off + r * (NN + 1);
    int tid = threadIdx.x, lane = tid & 63, w = tid >> 6;
    if (tid == 0) s_carry = 0;
    __syncthreads();
    for (int base = 0; base < NN; base += 256) {
        int i = base + tid;
        int v = (i < NN) ? c[i] : 0;
        int x = v;
#pragma unroll
        for (int s = 1; s < 64; s <<= 1) {
            int y = __shfl_up(x, (unsigned)s);
            if (lane >= s) x += y;
        }
        if (lane == 63) wsum[w] = x;
        __syncthreads();
        int wbase = 0;
#pragma unroll
        for (int j = 0; j < 3; ++j) wbase += (j < w) ? wsum[j] : 0;
        int excl = s_carry + wbase + x - v;
        if (i < NN) o[i] = excl;
        __syncthreads();
        if (tid == 255) s_carry += wbase + x;  // wsum[0..2] + inclusive of wave 3
        // s_carry write is ordered before next tile's first __syncthreads
    }
    __syncthreads();
    if (tid == 0) o[NN] = s_carry;
}

// ---------------- CSR fill (LDS counters, no global atomics) ----------------
// grid: 9 rel x 4 ranges = 36 blocks
__global__ __launch_bounds__(256) void k_fill(const int* __restrict__ edges,
                                              const int* __restrict__ off,
                                              int* __restrict__ esrc) {
    __shared__ int lcur[RANGE];
    int bid = blockIdx.x;
    int r = bid >> 2;
    int p = bid & 3;
    int base = p * RANGE;
    int tid = threadIdx.x;
    const int* orow = off + r * (NN + 1) + base;
    for (int i = tid; i < RANGE; i += 256) lcur[i] = orow[i];
    __syncthreads();
    const int* es = edges + (size_t)r * 2 * EE;
    const int* ed = es + EE;
    int* eo = esrc + (size_t)r * EE;
    for (int e = tid; e < EE; e += 256) {
        int dst = ed[e] - base;
        int src = es[e];
        if ((unsigned)dst < (unsigned)RANGE) {
            int pos = atomicAdd(&lcur[dst], 1);
            eo[pos] = src;
        }
    }
}

// ---------------- bias init -------------------------------------------------
__global__ void k_bias_init(const float* __restrict__ b, float* __restrict__ H) {
    int idx = blockIdx.x * blockDim.x + threadIdx.x; // float4 index into [3][NN][32]
    const int total = 3 * NN * 32;
    if (idx >= total) return;
    int t = idx / (NN * 32);
    int c4 = idx & 31;
    float4 s = make_float4(0.f, 0.f, 0.f, 0.f);
#pragma unroll
    for (int j = 0; j < 4; ++j) {
        int r = d_rel_of_type[t][j];
        if (r >= 0) {
            float4 bv = *reinterpret_cast<const float4*>(b + r * 128 + c4 * 4);
            s.x += bv.x; s.y += bv.y; s.z += bv.z; s.w += bv.w;
        }
    }
    *reinterpret_cast<float4*>((float*)H + (size_t)idx * 4) = s;
}

// ---------------- fused aggregate + GEMM ------------------------------------
// block: 256 threads, owns 64 dst rows. Phase 1: CSR gather of normalized src
// features into LDS A-tile [64][132]. Phase 2: A @ W (K=128, N=128), thread
// micro-tile 4x8, accumulate into H.
template <int RELU>
__global__ __launch_bounds__(256) void k_relgemm(const float* __restrict__ xin,
                                                 const int* __restrict__ off,
                                                 const int* __restrict__ esrc,
                                                 const float* __restrict__ ns,
                                                 const float* __restrict__ nd,
                                                 const float* __restrict__ W,
                                                 float* __restrict__ H) {
    __shared__ float sA[64 * 132];  // [row][k], stride 132 (4-aligned for float4)
    __shared__ float sW[32 * 128];  // [k][col] chunk
    int tid = threadIdx.x, lane = tid & 63, w = tid >> 6;
    int row0 = blockIdx.x * 64;

    // ---- phase 1: gather ----
    for (int rr = w; rr < 64; rr += 4) {
        int d = row0 + rr;
        float a0 = 0.f, a1 = 0.f;
        if (d < NN) {
            int e0 = off[d], e1 = off[d + 1];
            for (int e = e0; e < e1; ++e) {
                int s = esrc[e];
                float wn = ns[s];
                float2 v = *reinterpret_cast<const float2*>(xin + (size_t)s * 128 + lane * 2);
                float v0 = v.x, v1 = v.y;
                if (RELU) { v0 = fmaxf(v0, 0.f); v1 = fmaxf(v1, 0.f); }
                a0 = fmaf(wn, v0, a0);
                a1 = fmaf(wn, v1, a1);
            }
            float nr = nd[d];
            a0 *= nr; a1 *= nr;
        }
        *reinterpret_cast<float2*>(&sA[rr * 132 + lane * 2]) = make_float2(a0, a1);
    }

    // ---- phase 2: GEMM ----
    int tx = tid & 15;  // cols tx*8 .. +7
    int ty = tid >> 4;  // rows ty*4 .. +3
    float acc[4][8] = {};
    for (int k0 = 0; k0 < 128; k0 += 32) {
        __syncthreads();  // (k0==0: also fences phase-1 sA writes)
#pragma unroll
        for (int t = tid; t < 1024; t += 256)
            *reinterpret_cast<float4*>(&sW[t * 4]) =
                *reinterpret_cast<const float4*>(W + (size_t)k0 * 128 + t * 4);
        __syncthreads();
#pragma unroll
        for (int k4 = 0; k4 < 8; ++k4) {
            float av[4][4];
#pragma unroll
            for (int i = 0; i < 4; ++i) {
                float4 a4 = *reinterpret_cast<const float4*>(
                    &sA[(ty * 4 + i) * 132 + k0 + k4 * 4]);
                av[i][0] = a4.x; av[i][1] = a4.y; av[i][2] = a4.z; av[i][3] = a4.w;
            }
#pragma unroll
            for (int j = 0; j < 4; ++j) {
                int k = k4 * 4 + j;
                float4 w0 = *reinterpret_cast<const float4*>(&sW[k * 128 + tx * 8]);
                float4 w1 = *reinterpret_cast<const float4*>(&sW[k * 128 + tx * 8 + 4]);
                float wv[8] = {w0.x, w0.y, w0.z, w0.w, w1.x, w1.y, w1.z, w1.w};
#pragma unroll
                for (int i = 0; i < 4; ++i)
#pragma unroll
                    for (int jj = 0; jj < 8; ++jj)
                        acc[i][jj] = fmaf(av[i][j], wv[jj], acc[i][jj]);
            }
        }
    }

    // ---- epilogue: H += acc ----
#pragma unroll
    for (int i = 0; i < 4; ++i) {
        int grow = row0 + ty * 4 + i;
        if (grow < NN) {
            float* hp = H + (size_t)grow * 128 + tx * 8;
            float4 h0 = *reinterpret_cast<float4*>(hp);
            float4 h1v = *reinterpret_cast<float4*>(hp + 4);
            h0.x += acc[i][0]; h0.y += acc[i][1]; h0.z += acc[i][2]; h0.w += acc[i][3];
            h1v.x += acc[i][4]; h1v.y += acc[i][5]; h1v.z += acc[i][6]; h1v.w += acc[i][7];
            *reinterpret_cast<float4*>(hp) = h0;
            *reinterpret_cast<float4*>(hp + 4) = h1v;
        }
    }
}

// ---------------- classifier: out = relu(H) @ Wc + bc -----------------------
__global__ __launch_bounds__(256) void k_classifier(const float* __restrict__ H,
                                                    const float* __restrict__ Wc,
                                                    const float* __restrict__ bc,
                                                    float* __restrict__ out) {
    __shared__ float sW[128 * 16];
    __shared__ float sb[16];
    int tid = threadIdx.x;
#pragma unroll
    for (int i = tid; i < 2048; i += 256) sW[i] = Wc[i];
    if (tid < 16) sb[tid] = bc[tid];
    __syncthreads();
    int node = blockIdx.x * 64 + (tid >> 2);
    if (node >= 3 * NN) return;
    int cg = (tid & 3) << 2;
    const float* h = H + (size_t)node * 128;
    float acc0 = 0.f, acc1 = 0.f, acc2 = 0.f, acc3 = 0.f;
#pragma unroll 4
    for (int k0 = 0; k0 < 128; k0 += 4) {
        float4 a4 = *reinterpret_cast<const float4*>(h + k0);
        float a;
        a = fmaxf(a4.x, 0.f);
        { float4 wv = *reinterpret_cast<const float4*>(&sW[(k0 + 0) * 16 + cg]);
          acc0 = fmaf(a, wv.x, acc0); acc1 = fmaf(a, wv.y, acc1);
          acc2 = fmaf(a, wv.z, acc2); acc3 = fmaf(a, wv.w, acc3); }
        a = fmaxf(a4.y, 0.f);
        { float4 wv = *reinterpret_cast<const float4*>(&sW[(k0 + 1) * 16 + cg]);
          acc0 = fmaf(a, wv.x, acc0); acc1 = fmaf(a, wv.y, acc1);
          acc2 = fmaf(a, wv.z, acc2); acc3 = fmaf(a, wv.w, acc3); }
        a = fmaxf(a4.z, 0.f);
        { float4 wv = *reinterpret_cast<const float4*>(&sW[(k0 + 2) * 16 + cg]);
          acc0 = fmaf(a, wv.x, acc0); acc1 = fmaf(a, wv.y, acc1);
          acc2 = fmaf(a, wv.z, acc2); acc3 = fmaf(a, wv.w, acc3); }
        a = fmaxf(a4.w, 0.f);
        { float4 wv = *reinterpret_cast<const float4*>(&sW[(k0 + 3) * 16 + cg]);
          acc0 = fmaf(a, wv.x, acc0); acc1 = fmaf(a, wv.y, acc1);
          acc2 = fmaf(a, wv.z, acc2); acc3 = fmaf(a, wv.w, acc3); }
    }
    float4 o = make_float4(acc0 + sb[cg], acc1 + sb[cg + 1],
                           acc2 + sb[cg + 2], acc3 + sb[cg + 3]);
    *reinterpret_cast<float4*>(out + (size_t)node * 16 + cg) = o;
}

// ---------------------------------------------------------------------------
extern "C" void kernel_launch(void* const* d_in, const int* in_sizes, int n_in,
                              void* d_out, int out_size, void* d_ws, size_t ws_size,
                              hipStream_t stream) {
    const float* x0 = (const float*)d_in[0];
    const float* x1 = (const float*)d_in[1];
    const float* x2 = (const float*)d_in[2];
    const float* W1 = (const float*)d_in[3];
    const float* b1 = (const float*)d_in[4];
    const float* W2 = (const float*)d_in[5];
    const float* b2 = (const float*)d_in[6];
    const float* Wc = (const float*)d_in[7];
    const float* bc = (const float*)d_in[8];
    const int* edges = (const int*)d_in[9];
    const float* x[3] = {x0, x1, x2};

    const int REL_S[9] = {0, 1, 1, 0, 2, 2, 0, 2, 1};
    const int REL_D[9] = {2, 2, 0, 0, 1, 0, 0, 2, 1};

    // workspace carve-up
    char* p = (char*)d_ws;
    auto alloc = [&](size_t bytes) -> void* {
        void* r = (void*)p;
        p += (bytes + 255) & ~(size_t)255;
        return r;
    };
    int*   deg  = (int*)  alloc((size_t)2 * 9 * NN * sizeof(int)); // deg_s | deg_d
    float* ns   = (float*)alloc((size_t)9 * NN * sizeof(float));
    float* nd   = (float*)alloc((size_t)9 * NN * sizeof(float));
    int*   off  = (int*)  alloc((size_t)9 * (NN + 1) * sizeof(int));
    int*   esrc = (int*)  alloc((size_t)9 * EE * sizeof(int));
    float* h1   = (float*)alloc((size_t)3 * NN * 128 * sizeof(float));
    float* h2   = (float*)alloc((size_t)3 * NN * 128 * sizeof(float));
    int* deg_s = deg;
    int* deg_d = deg + 9 * NN;

    // ---- CSR build (no global atomics), reused by both layers ----
    k_hist<<<72, 256, 0, stream>>>(edges, deg_s, deg_d);
    k_norms<<<(9 * NN + 255) / 256, 256, 0, stream>>>(deg_s, deg_d, ns, nd);
    k_offsets<<<9, 256, 0, stream>>>(deg_d, off);
    k_fill<<<36, 256, 0, stream>>>(edges, off, esrc);

    const int gemm_blocks = (NN + 63) / 64;       // 782
    const int bias_blocks = (3 * NN * 32) / 256;  // 18750

    // ---- layer 1 ----
    k_bias_init<<<bias_blocks, 256, 0, stream>>>(b1, h1);
    for (int r = 0; r < 9; ++r) {
        int s = REL_S[r], d = REL_D[r];
        k_relgemm<0><<<gemm_blocks, 256, 0, stream>>>(
            x[s], off + r * (NN + 1), esrc + (size_t)r * EE,
            ns + r * NN, nd + r * NN, W1 + (size_t)r * 128 * 128,
            h1 + (size_t)d * NN * 128);
    }

    // ---- layer 2 (input = relu(h1), folded into gather) ----
    k_bias_init<<<bias_blocks, 256, 0, stream>>>(b2, h2);
    for (int r = 0; r < 9; ++r) {
        int s = REL_S[r], d = REL_D[r];
        k_relgemm<1><<<gemm_blocks, 256, 0, stream>>>(
            h1 + (size_t)s * NN * 128, off + r * (NN + 1), esrc + (size_t)r * EE,
            ns + r * NN, nd + r * NN, W2 + (size_t)r * 128 * 128,
            h2 + (size_t)d * NN * 128);
    }

    // ---- classifier: out = relu(h2) @ Wc + bc ----
    k_classifier<<<(3 * NN + 63) / 64, 256, 0, stream>>>(h2, Wc, bc, (float*)d_out);
}

// Round 3
// 1715.708 us; speedup vs baseline: 2.8943x; 2.8943x over previous
//
#include <hip/hip_runtime.h>
#include <hip/hip_bf16.h>

// ---------------------------------------------------------------------------
// Hetero-GCN (3 node types, 9 relations), 2 GraphConv layers + classifier.
// Round 3:
//  - UN-fuse agg/gemm (round-2 fusion starved the gather of TLP: 782 blocks
//    @ 3/CU vs 12500 blocks; k_fill/k_hist at 36/72 blocks were 30x worse).
//  - Degrees via chunked LDS histograms, 288 blocks, no global atomics.
//  - Fill via global atomics (full grid), emitting int2{src, ns[src]} so the
//    gather loop drops one dependent load.
//  - k_agg: 4-way unrolled edge loop, 4 independent row loads in flight.
// All fp32.
// ---------------------------------------------------------------------------

#define NN 50000
#define EE 400000
#define NRG 2            // node ranges for histogram
#define RGN (NN / NRG)   // 25000 nodes per range
#define HCH 8            // edge chunks
#define HEG (EE / HCH)   // 50000 edges per chunk

// REL = [(0,2),(1,2),(1,0),(0,0),(2,1),(2,0),(0,0),(2,2),(1,1)]
__device__ __constant__ int d_rel_of_type[3][4] = {
    {2, 3, 5, 6},   // dst type 0
    {4, 8, -1, -1}, // dst type 1
    {0, 1, 7, -1},  // dst type 2
};

// ---------------- degree histogram (chunked, LDS, no global atomics) --------
// grid: 18 tasks (9 rel x {src,dst}) x NRG ranges x HCH chunks = 288 blocks
// bins pack two nodes per u32 (lo/hi u16); per-chunk count <= 50000 < 65536.
__global__ __launch_bounds__(256) void k_hist(const int* __restrict__ edges,
                                              unsigned* __restrict__ hist) {
    __shared__ unsigned bins[RGN / 2];  // 12500 u32 = 50 KB
    int bid = blockIdx.x;
    int task = bid >> 4;           // r*2 + side
    int rem = bid & 15;
    int rg = rem >> 3;
    int c = rem & 7;
    int r = task >> 1, side = task & 1;
    int tid = threadIdx.x;
    for (int i = tid; i < RGN / 2; i += 256) bins[i] = 0;
    __syncthreads();
    const int* ea = edges + (size_t)r * 2 * EE + (size_t)side * EE + (size_t)c * HEG;
    int base = rg * RGN;
    for (int e = tid; e < HEG; e += 256) {
        int idx = ea[e] - base;
        if ((unsigned)idx < (unsigned)RGN)
            atomicAdd(&bins[idx >> 1], (idx & 1) ? 65536u : 1u);
    }
    __syncthreads();
    unsigned* ho = hist + ((size_t)(task * NRG + rg) * HCH + c) * (RGN / 2);
    for (int i = tid; i < RGN / 2; i += 256) ho[i] = bins[i];
}

// ---------------- reduce histograms -> ns, nd, deg_d ------------------------
__global__ void k_sums(const unsigned* __restrict__ hist, float* __restrict__ ns,
                       float* __restrict__ nd, int* __restrict__ deg_d) {
    int i = blockIdx.x * blockDim.x + threadIdx.x;
    if (i >= 9 * (NN / 2)) return;
    int r = i / (NN / 2);
    int ps = i - r * (NN / 2);        // node-pair slot within relation
    int rg = ps / (RGN / 2);
    int slot = ps - rg * (RGN / 2);
    const unsigned* hs = hist + ((size_t)((r * 2 + 0) * NRG + rg) * HCH) * (RGN / 2) + slot;
    const unsigned* hd = hist + ((size_t)((r * 2 + 1) * NRG + rg) * HCH) * (RGN / 2) + slot;
    unsigned slo = 0, shi = 0, dlo = 0, dhi = 0;
#pragma unroll
    for (int c = 0; c < HCH; ++c) {
        unsigned a = hs[(size_t)c * (RGN / 2)];
        unsigned b = hd[(size_t)c * (RGN / 2)];
        slo += a & 0xffffu; shi += a >> 16;
        dlo += b & 0xffffu; dhi += b >> 16;
    }
    int n0 = 2 * ps;
    ns[r * NN + n0]     = slo ? rsqrtf((float)slo) : 0.f;
    ns[r * NN + n0 + 1] = shi ? rsqrtf((float)shi) : 0.f;
    nd[r * NN + n0]     = dlo ? rsqrtf((float)dlo) : 0.f;
    nd[r * NN + n0 + 1] = dhi ? rsqrtf((float)dhi) : 0.f;
    deg_d[r * NN + n0]     = (int)dlo;
    deg_d[r * NN + n0 + 1] = (int)dhi;
}

// ---------------- exclusive scan of in-degrees -> CSR offsets ---------------
// 9 blocks (one per relation); shfl wave scan. Also seeds cur[].
__global__ __launch_bounds__(256) void k_offsets(const int* __restrict__ deg_d,
                                                 int* __restrict__ off,
                                                 int* __restrict__ cur) {
    __shared__ int wsum[4];
    __shared__ int s_carry;
    int r = blockIdx.x;
    const int* c = deg_d + r * NN;
    int* o = off + r * (NN + 1);
    int* cu = cur + r * NN;
    int tid = threadIdx.x, lane = tid & 63, w = tid >> 6;
    if (tid == 0) s_carry = 0;
    __syncthreads();
    for (int base = 0; base < NN; base += 256) {
        int i = base + tid;
        int v = (i < NN) ? c[i] : 0;
        int x = v;
#pragma unroll
        for (int s = 1; s < 64; s <<= 1) {
            int y = __shfl_up(x, (unsigned)s);
            if (lane >= s) x += y;
        }
        if (lane == 63) wsum[w] = x;
        __syncthreads();
        int wbase = 0;
#pragma unroll
        for (int j = 0; j < 3; ++j) wbase += (j < w) ? wsum[j] : 0;
        int excl = s_carry + wbase + x - v;
        if (i < NN) { o[i] = excl; cu[i] = excl; }
        __syncthreads();
        if (tid == 255) s_carry += wbase + x;
    }
    __syncthreads();
    if (tid == 0) o[NN] = s_carry;
}

// ---------------- CSR fill (global atomics, full grid) ----------------------
// writes int2 {src, ns[src]} so the gather loop loses a dependent load
__global__ __launch_bounds__(256) void k_fill(const int* __restrict__ edges,
                                              const float* __restrict__ ns,
                                              int* __restrict__ cur,
                                              int2* __restrict__ esn) {
    int i = blockIdx.x * blockDim.x + threadIdx.x;
    if (i >= 9 * EE) return;
    int r = i / EE;
    int e = i - r * EE;
    int src = edges[(size_t)r * 2 * EE + e];
    int dst = edges[(size_t)r * 2 * EE + EE + e];
    int pos = atomicAdd(&cur[r * NN + dst], 1);
    esn[(size_t)r * EE + pos] = make_int2(src, __float_as_int(ns[r * NN + src]));
}

// ---------------- bias init -------------------------------------------------
__global__ void k_bias_init(const float* __restrict__ b, float* __restrict__ H) {
    int idx = blockIdx.x * blockDim.x + threadIdx.x; // float4 index into [3][NN][32]
    const int total = 3 * NN * 32;
    if (idx >= total) return;
    int t = idx / (NN * 32);
    int c4 = idx & 31;
    float4 s = make_float4(0.f, 0.f, 0.f, 0.f);
#pragma unroll
    for (int j = 0; j < 4; ++j) {
        int r = d_rel_of_type[t][j];
        if (r >= 0) {
            float4 bv = *reinterpret_cast<const float4*>(b + r * 128 + c4 * 4);
            s.x += bv.x; s.y += bv.y; s.z += bv.z; s.w += bv.w;
        }
    }
    *reinterpret_cast<float4*>((float*)H + (size_t)idx * 4) = s;
}

// ---------------- aggregation (CSR gather, one wave per dst row) ------------
// 4-way unrolled edge loop: 4 independent feature-row loads in flight.
template <int RELU>
__global__ __launch_bounds__(256) void k_agg(const float* __restrict__ xin,
                                             const int* __restrict__ off,
                                             const int2* __restrict__ esn,
                                             const float* __restrict__ nd,
                                             float* __restrict__ A) {
    int wave = (blockIdx.x * blockDim.x + threadIdx.x) >> 6;
    int lane = threadIdx.x & 63;
    if (wave >= NN) return;
    int e0 = off[wave], e1 = off[wave + 1];
    float a0 = 0.f, a1 = 0.f, b0 = 0.f, b1 = 0.f;
    float c0 = 0.f, c1 = 0.f, d0 = 0.f, d1 = 0.f;
    int e = e0;
    for (; e + 4 <= e1; e += 4) {
        int2 p0 = esn[e], p1 = esn[e + 1], p2 = esn[e + 2], p3 = esn[e + 3];
        float2 v0 = *reinterpret_cast<const float2*>(xin + (size_t)p0.x * 128 + lane * 2);
        float2 v1 = *reinterpret_cast<const float2*>(xin + (size_t)p1.x * 128 + lane * 2);
        float2 v2 = *reinterpret_cast<const float2*>(xin + (size_t)p2.x * 128 + lane * 2);
        float2 v3 = *reinterpret_cast<const float2*>(xin + (size_t)p3.x * 128 + lane * 2);
        if (RELU) {
            v0.x = fmaxf(v0.x, 0.f); v0.y = fmaxf(v0.y, 0.f);
            v1.x = fmaxf(v1.x, 0.f); v1.y = fmaxf(v1.y, 0.f);
            v2.x = fmaxf(v2.x, 0.f); v2.y = fmaxf(v2.y, 0.f);
            v3.x = fmaxf(v3.x, 0.f); v3.y = fmaxf(v3.y, 0.f);
        }
        float w0 = __int_as_float(p0.y), w1 = __int_as_float(p1.y);
        float w2 = __int_as_float(p2.y), w3 = __int_as_float(p3.y);
        a0 = fmaf(w0, v0.x, a0); a1 = fmaf(w0, v0.y, a1);
        b0 = fmaf(w1, v1.x, b0); b1 = fmaf(w1, v1.y, b1);
        c0 = fmaf(w2, v2.x, c0); c1 = fmaf(w2, v2.y, c1);
        d0 = fmaf(w3, v3.x, d0); d1 = fmaf(w3, v3.y, d1);
    }
    for (; e < e1; ++e) {
        int2 p = esn[e];
        float2 v = *reinterpret_cast<const float2*>(xin + (size_t)p.x * 128 + lane * 2);
        if (RELU) { v.x = fmaxf(v.x, 0.f); v.y = fmaxf(v.y, 0.f); }
        float w = __int_as_float(p.y);
        a0 = fmaf(w, v.x, a0); a1 = fmaf(w, v.y, a1);
    }
    float nr = nd[wave];
    float2 o = make_float2(((a0 + b0) + (c0 + d0)) * nr,
                           ((a1 + b1) + (c1 + d1)) * nr);
    *reinterpret_cast<float2*>(A + (size_t)wave * 128 + lane * 2) = o;
}

// ---------------- GEMM: H += A @ W  (M=NN, K=128, N=128) --------------------
__global__ __launch_bounds__(256) void k_gemm(const float* __restrict__ A,
                                              const float* __restrict__ W,
                                              float* __restrict__ H) {
    __shared__ float sA[32 * 68];   // [k][row], padded stride 68
    __shared__ float sW[32 * 128];  // [k][col]
    int tid = threadIdx.x;
    int row0 = blockIdx.x * 64;
    int tx = tid & 15;   // col group: cols tx*8 .. tx*8+7
    int ty = tid >> 4;   // row group: rows ty*4 .. ty*4+3
    float acc[4][8] = {};
    for (int k0 = 0; k0 < 128; k0 += 32) {
        __syncthreads();
#pragma unroll
        for (int t = tid; t < 512; t += 256) {
            int rr = t >> 3;
            int kk = (t & 7) << 2;
            int grow = row0 + rr;
            float4 v = make_float4(0.f, 0.f, 0.f, 0.f);
            if (grow < NN)
                v = *reinterpret_cast<const float4*>(A + (size_t)grow * 128 + k0 + kk);
            sA[(kk + 0) * 68 + rr] = v.x;
            sA[(kk + 1) * 68 + rr] = v.y;
            sA[(kk + 2) * 68 + rr] = v.z;
            sA[(kk + 3) * 68 + rr] = v.w;
        }
#pragma unroll
        for (int t = tid; t < 1024; t += 256) {
            *reinterpret_cast<float4*>(&sW[t * 4]) =
                *reinterpret_cast<const float4*>(W + (size_t)k0 * 128 + t * 4);
        }
        __syncthreads();
#pragma unroll
        for (int k = 0; k < 32; ++k) {
            float4 av = *reinterpret_cast<const float4*>(&sA[k * 68 + ty * 4]);
            float4 w0 = *reinterpret_cast<const float4*>(&sW[k * 128 + tx * 8]);
            float4 w1 = *reinterpret_cast<const float4*>(&sW[k * 128 + tx * 8 + 4]);
            float a[4] = {av.x, av.y, av.z, av.w};
            float wv[8] = {w0.x, w0.y, w0.z, w0.w, w1.x, w1.y, w1.z, w1.w};
#pragma unroll
            for (int i = 0; i < 4; ++i)
#pragma unroll
                for (int j = 0; j < 8; ++j)
                    acc[i][j] = fmaf(a[i], wv[j], acc[i][j]);
        }
    }
#pragma unroll
    for (int i = 0; i < 4; ++i) {
        int grow = row0 + ty * 4 + i;
        if (grow < NN) {
            float* hp = H + (size_t)grow * 128 + tx * 8;
            float4 h0 = *reinterpret_cast<float4*>(hp);
            float4 h1v = *reinterpret_cast<float4*>(hp + 4);
            h0.x += acc[i][0]; h0.y += acc[i][1]; h0.z += acc[i][2]; h0.w += acc[i][3];
            h1v.x += acc[i][4]; h1v.y += acc[i][5]; h1v.z += acc[i][6]; h1v.w += acc[i][7];
            *reinterpret_cast<float4*>(hp) = h0;
            *reinterpret_cast<float4*>(hp + 4) = h1v;
        }
    }
}

// ---------------- classifier: out = relu(H) @ Wc + bc -----------------------
__global__ __launch_bounds__(256) void k_classifier(const float* __restrict__ H,
                                                    const float* __restrict__ Wc,
                                                    const float* __restrict__ bc,
                                                    float* __restrict__ out) {
    __shared__ float sW[128 * 16];
    __shared__ float sb[16];
    int tid = threadIdx.x;
#pragma unroll
    for (int i = tid; i < 2048; i += 256) sW[i] = Wc[i];
    if (tid < 16) sb[tid] = bc[tid];
    __syncthreads();
    int node = blockIdx.x * 64 + (tid >> 2);
    if (node >= 3 * NN) return;
    int cg = (tid & 3) << 2;
    const float* h = H + (size_t)node * 128;
    float acc0 = 0.f, acc1 = 0.f, acc2 = 0.f, acc3 = 0.f;
#pragma unroll 4
    for (int k0 = 0; k0 < 128; k0 += 4) {
        float4 a4 = *reinterpret_cast<const float4*>(h + k0);
        float a;
        a = fmaxf(a4.x, 0.f);
        { float4 wv = *reinterpret_cast<const float4*>(&sW[(k0 + 0) * 16 + cg]);
          acc0 = fmaf(a, wv.x, acc0); acc1 = fmaf(a, wv.y, acc1);
          acc2 = fmaf(a, wv.z, acc2); acc3 = fmaf(a, wv.w, acc3); }
        a = fmaxf(a4.y, 0.f);
        { float4 wv = *reinterpret_cast<const float4*>(&sW[(k0 + 1) * 16 + cg]);
          acc0 = fmaf(a, wv.x, acc0); acc1 = fmaf(a, wv.y, acc1);
          acc2 = fmaf(a, wv.z, acc2); acc3 = fmaf(a, wv.w, acc3); }
        a = fmaxf(a4.z, 0.f);
        { float4 wv = *reinterpret_cast<const float4*>(&sW[(k0 + 2) * 16 + cg]);
          acc0 = fmaf(a, wv.x, acc0); acc1 = fmaf(a, wv.y, acc1);
          acc2 = fmaf(a, wv.z, acc2); acc3 = fmaf(a, wv.w, acc3); }
        a = fmaxf(a4.w, 0.f);
        { float4 wv = *reinterpret_cast<const float4*>(&sW[(k0 + 3) * 16 + cg]);
          acc0 = fmaf(a, wv.x, acc0); acc1 = fmaf(a, wv.y, acc1);
          acc2 = fmaf(a, wv.z, acc2); acc3 = fmaf(a, wv.w, acc3); }
    }
    float4 o = make_float4(acc0 + sb[cg], acc1 + sb[cg + 1],
                           acc2 + sb[cg + 2], acc3 + sb[cg + 3]);
    *reinterpret_cast<float4*>(out + (size_t)node * 16 + cg) = o;
}

// ---------------------------------------------------------------------------
extern "C" void kernel_launch(void* const* d_in, const int* in_sizes, int n_in,
                              void* d_out, int out_size, void* d_ws, size_t ws_size,
                              hipStream_t stream) {
    const float* x0 = (const float*)d_in[0];
    const float* x1 = (const float*)d_in[1];
    const float* x2 = (const float*)d_in[2];
    const float* W1 = (const float*)d_in[3];
    const float* b1 = (const float*)d_in[4];
    const float* W2 = (const float*)d_in[5];
    const float* b2 = (const float*)d_in[6];
    const float* Wc = (const float*)d_in[7];
    const float* bc = (const float*)d_in[8];
    const int* edges = (const int*)d_in[9];
    const float* x[3] = {x0, x1, x2};

    const int REL_S[9] = {0, 1, 1, 0, 2, 2, 0, 2, 1};
    const int REL_D[9] = {2, 2, 0, 0, 1, 0, 0, 2, 1};

    // ---- workspace carve-up with overlays (~212 MB peak) ----
    char* p = (char*)d_ws;
    auto alloc = [&](size_t bytes) -> void* {
        void* r = (void*)p;
        p += (bytes + 255) & ~(size_t)255;
        return r;
    };
    float* h2 = (float*)alloc((size_t)3 * NN * 128 * sizeof(float));  // 76.8 MB
    unsigned* hist = (unsigned*)h2;   // alias: hist dead after k_sums, h2 written later
    float* h1 = (float*)alloc((size_t)3 * NN * 128 * sizeof(float));  // 76.8 MB
    float* ns = (float*)h1;           // alias: ns dead after k_fill
    int* cur = (int*)(h1 + 9 * NN);   // alias: cur dead after k_fill
    int* deg_d = (int*)(h1 + 18 * NN);// alias: deg_d dead after k_offsets
    float* Abuf = (float*)alloc((size_t)NN * 128 * sizeof(float));    // 25.6 MB
    int* off = (int*)alloc((size_t)9 * (NN + 1) * sizeof(int));
    float* nd = (float*)alloc((size_t)9 * NN * sizeof(float));
    int2* esn = (int2*)alloc((size_t)9 * EE * sizeof(int2));          // 28.8 MB

    // ---- CSR build (reused by both layers) ----
    k_hist<<<288, 256, 0, stream>>>(edges, hist);
    k_sums<<<(9 * (NN / 2) + 255) / 256, 256, 0, stream>>>(hist, ns, nd, deg_d);
    k_offsets<<<9, 256, 0, stream>>>(deg_d, off, cur);
    k_fill<<<(9 * EE + 255) / 256, 256, 0, stream>>>(edges, ns, cur, esn);

    const int agg_blocks = (NN * 64) / 256;       // 12500
    const int gemm_blocks = (NN + 63) / 64;       // 782
    const int bias_blocks = (3 * NN * 32) / 256;  // 18750

    // ---- layer 1 ----
    k_bias_init<<<bias_blocks, 256, 0, stream>>>(b1, h1);
    for (int r = 0; r < 9; ++r) {
        int s = REL_S[r], d = REL_D[r];
        k_agg<0><<<agg_blocks, 256, 0, stream>>>(x[s], off + r * (NN + 1),
                                                 esn + (size_t)r * EE,
                                                 nd + r * NN, Abuf);
        k_gemm<<<gemm_blocks, 256, 0, stream>>>(Abuf, W1 + (size_t)r * 128 * 128,
                                                h1 + (size_t)d * NN * 128);
    }

    // ---- layer 2 (input = relu(h1), folded into gather) ----
    k_bias_init<<<bias_blocks, 256, 0, stream>>>(b2, h2);
    for (int r = 0; r < 9; ++r) {
        int s = REL_S[r], d = REL_D[r];
        k_agg<1><<<agg_blocks, 256, 0, stream>>>(h1 + (size_t)s * NN * 128,
                                                 off + r * (NN + 1),
                                                 esn + (size_t)r * EE,
                                                 nd + r * NN, Abuf);
        k_gemm<<<gemm_blocks, 256, 0, stream>>>(Abuf, W2 + (size_t)r * 128 * 128,
                                                h2 + (size_t)d * NN * 128);
    }

    // ---- classifier: out = relu(h2) @ Wc + bc ----
    k_classifier<<<(3 * NN + 63) / 64, 256, 0, stream>>>(h2, Wc, bc, (float*)d_out);
}

// Round 4
// 1650.243 us; speedup vs baseline: 3.0091x; 1.0397x over previous
//
#include <hip/hip_runtime.h>
#include <hip/hip_bf16.h>

// ---------------------------------------------------------------------------
// Hetero-GCN (3 node types, 9 relations), 2 GraphConv layers + classifier.
// Round 4:
//  - esrc is 4B (src only); ns[s] re-read in k_agg (L2-resident). Halves the
//    k_fill scatter region (was 8x write-amplified: 235MB for 28.8MB useful).
//  - Non-temporal loads for streaming edge reads in k_fill.
//  - Bias folded into GEMM epilogue (STORE for first relation per dst type,
//    ACCUM after): kills k_bias_init and first-relation H reads (~300MB).
// All fp32.
// ---------------------------------------------------------------------------

#define NN 50000
#define EE 400000
#define NRG 2            // node ranges for histogram
#define RGN (NN / NRG)   // 25000 nodes per range
#define HCH 8            // edge chunks
#define HEG (EE / HCH)   // 50000 edges per chunk

// ---------------- degree histogram (chunked, LDS, no global atomics) --------
// grid: 18 tasks (9 rel x {src,dst}) x NRG ranges x HCH chunks = 288 blocks
__global__ __launch_bounds__(256) void k_hist(const int* __restrict__ edges,
                                              unsigned* __restrict__ hist) {
    __shared__ unsigned bins[RGN / 2];  // 12500 u32 = 50 KB
    int bid = blockIdx.x;
    int task = bid >> 4;           // r*2 + side
    int rem = bid & 15;
    int rg = rem >> 3;
    int c = rem & 7;
    int r = task >> 1, side = task & 1;
    int tid = threadIdx.x;
    for (int i = tid; i < RGN / 2; i += 256) bins[i] = 0;
    __syncthreads();
    const int* ea = edges + (size_t)r * 2 * EE + (size_t)side * EE + (size_t)c * HEG;
    int base = rg * RGN;
    for (int e = tid; e < HEG; e += 256) {
        int idx = __builtin_nontemporal_load(&ea[e]) - base;
        if ((unsigned)idx < (unsigned)RGN)
            atomicAdd(&bins[idx >> 1], (idx & 1) ? 65536u : 1u);
    }
    __syncthreads();
    unsigned* ho = hist + ((size_t)(task * NRG + rg) * HCH + c) * (RGN / 2);
    for (int i = tid; i < RGN / 2; i += 256) ho[i] = bins[i];
}

// ---------------- reduce histograms -> ns, nd, deg_d ------------------------
__global__ void k_sums(const unsigned* __restrict__ hist, float* __restrict__ ns,
                       float* __restrict__ nd, int* __restrict__ deg_d) {
    int i = blockIdx.x * blockDim.x + threadIdx.x;
    if (i >= 9 * (NN / 2)) return;
    int r = i / (NN / 2);
    int ps = i - r * (NN / 2);        // node-pair slot within relation
    int rg = ps / (RGN / 2);
    int slot = ps - rg * (RGN / 2);
    const unsigned* hs = hist + ((size_t)((r * 2 + 0) * NRG + rg) * HCH) * (RGN / 2) + slot;
    const unsigned* hd = hist + ((size_t)((r * 2 + 1) * NRG + rg) * HCH) * (RGN / 2) + slot;
    unsigned slo = 0, shi = 0, dlo = 0, dhi = 0;
#pragma unroll
    for (int c = 0; c < HCH; ++c) {
        unsigned a = hs[(size_t)c * (RGN / 2)];
        unsigned b = hd[(size_t)c * (RGN / 2)];
        slo += a & 0xffffu; shi += a >> 16;
        dlo += b & 0xffffu; dhi += b >> 16;
    }
    int n0 = 2 * ps;
    ns[r * NN + n0]     = slo ? rsqrtf((float)slo) : 0.f;
    ns[r * NN + n0 + 1] = shi ? rsqrtf((float)shi) : 0.f;
    nd[r * NN + n0]     = dlo ? rsqrtf((float)dlo) : 0.f;
    nd[r * NN + n0 + 1] = dhi ? rsqrtf((float)dhi) : 0.f;
    deg_d[r * NN + n0]     = (int)dlo;
    deg_d[r * NN + n0 + 1] = (int)dhi;
}

// ---------------- exclusive scan of in-degrees -> CSR offsets ---------------
// 9 blocks (one per relation); shfl wave scan. Also seeds cur[].
__global__ __launch_bounds__(256) void k_offsets(const int* __restrict__ deg_d,
                                                 int* __restrict__ off,
                                                 int* __restrict__ cur) {
    __shared__ int wsum[4];
    __shared__ int s_carry;
    int r = blockIdx.x;
    const int* c = deg_d + r * NN;
    int* o = off + r * (NN + 1);
    int* cu = cur + r * NN;
    int tid = threadIdx.x, lane = tid & 63, w = tid >> 6;
    if (tid == 0) s_carry = 0;
    __syncthreads();
    for (int base = 0; base < NN; base += 256) {
        int i = base + tid;
        int v = (i < NN) ? c[i] : 0;
        int x = v;
#pragma unroll
        for (int s = 1; s < 64; s <<= 1) {
            int y = __shfl_up(x, (unsigned)s);
            if (lane >= s) x += y;
        }
        if (lane == 63) wsum[w] = x;
        __syncthreads();
        int wbase = 0;
#pragma unroll
        for (int j = 0; j < 3; ++j) wbase += (j < w) ? wsum[j] : 0;
        int excl = s_carry + wbase + x - v;
        if (i < NN) { o[i] = excl; cu[i] = excl; }
        __syncthreads();
        if (tid == 255) s_carry += wbase + x;
    }
    __syncthreads();
    if (tid == 0) o[NN] = s_carry;
}

// ---------------- CSR fill (global atomics, full grid, 4B payload) ----------
__global__ __launch_bounds__(256) void k_fill(const int* __restrict__ edges,
                                              int* __restrict__ cur,
                                              int* __restrict__ esrc) {
    int i = blockIdx.x * blockDim.x + threadIdx.x;
    if (i >= 9 * EE) return;
    int r = i / EE;
    int e = i - r * EE;
    int src = __builtin_nontemporal_load(&edges[(size_t)r * 2 * EE + e]);
    int dst = __builtin_nontemporal_load(&edges[(size_t)r * 2 * EE + EE + e]);
    int pos = atomicAdd(&cur[r * NN + dst], 1);
    esrc[(size_t)r * EE + pos] = src;
}

// ---------------- aggregation (CSR gather, one wave per dst row) ------------
// 4-way unrolled edge loop: 4 independent {ns, feature-row} loads in flight.
template <int RELU>
__global__ __launch_bounds__(256) void k_agg(const float* __restrict__ xin,
                                             const int* __restrict__ off,
                                             const int* __restrict__ esrc,
                                             const float* __restrict__ ns,
                                             const float* __restrict__ nd,
                                             float* __restrict__ A) {
    int wave = (blockIdx.x * blockDim.x + threadIdx.x) >> 6;
    int lane = threadIdx.x & 63;
    if (wave >= NN) return;
    int e0 = off[wave], e1 = off[wave + 1];
    float a0 = 0.f, a1 = 0.f, b0 = 0.f, b1 = 0.f;
    float c0 = 0.f, c1 = 0.f, d0 = 0.f, d1 = 0.f;
    int e = e0;
    for (; e + 4 <= e1; e += 4) {
        int s0 = esrc[e], s1 = esrc[e + 1], s2 = esrc[e + 2], s3 = esrc[e + 3];
        float w0 = ns[s0], w1 = ns[s1], w2 = ns[s2], w3 = ns[s3];
        float2 v0 = *reinterpret_cast<const float2*>(xin + (size_t)s0 * 128 + lane * 2);
        float2 v1 = *reinterpret_cast<const float2*>(xin + (size_t)s1 * 128 + lane * 2);
        float2 v2 = *reinterpret_cast<const float2*>(xin + (size_t)s2 * 128 + lane * 2);
        float2 v3 = *reinterpret_cast<const float2*>(xin + (size_t)s3 * 128 + lane * 2);
        if (RELU) {
            v0.x = fmaxf(v0.x, 0.f); v0.y = fmaxf(v0.y, 0.f);
            v1.x = fmaxf(v1.x, 0.f); v1.y = fmaxf(v1.y, 0.f);
            v2.x = fmaxf(v2.x, 0.f); v2.y = fmaxf(v2.y, 0.f);
            v3.x = fmaxf(v3.x, 0.f); v3.y = fmaxf(v3.y, 0.f);
        }
        a0 = fmaf(w0, v0.x, a0); a1 = fmaf(w0, v0.y, a1);
        b0 = fmaf(w1, v1.x, b0); b1 = fmaf(w1, v1.y, b1);
        c0 = fmaf(w2, v2.x, c0); c1 = fmaf(w2, v2.y, c1);
        d0 = fmaf(w3, v3.x, d0); d1 = fmaf(w3, v3.y, d1);
    }
    for (; e < e1; ++e) {
        int s = esrc[e];
        float w = ns[s];
        float2 v = *reinterpret_cast<const float2*>(xin + (size_t)s * 128 + lane * 2);
        if (RELU) { v.x = fmaxf(v.x, 0.f); v.y = fmaxf(v.y, 0.f); }
        a0 = fmaf(w, v.x, a0); a1 = fmaf(w, v.y, a1);
    }
    float nr = nd[wave];
    float2 o = make_float2(((a0 + b0) + (c0 + d0)) * nr,
                           ((a1 + b1) + (c1 + d1)) * nr);
    *reinterpret_cast<float2*>(A + (size_t)wave * 128 + lane * 2) = o;
}

// ---------------- GEMM: H (=|+=) A @ W + bias  (M=NN, K=128, N=128) ---------
// STORE=1: H = acc + bias (first relation for a dst type, kills H read)
// STORE=0: H += acc + bias
template <int STORE>
__global__ __launch_bounds__(256) void k_gemm(const float* __restrict__ A,
                                              const float* __restrict__ W,
                                              const float* __restrict__ bias,
                                              float* __restrict__ H) {
    __shared__ float sA[32 * 68];   // [k][row], padded stride 68
    __shared__ float sW[32 * 128];  // [k][col]
    int tid = threadIdx.x;
    int row0 = blockIdx.x * 64;
    int tx = tid & 15;   // col group: cols tx*8 .. tx*8+7
    int ty = tid >> 4;   // row group: rows ty*4 .. ty*4+3
    float acc[4][8] = {};
    for (int k0 = 0; k0 < 128; k0 += 32) {
        __syncthreads();
#pragma unroll
        for (int t = tid; t < 512; t += 256) {
            int rr = t >> 3;
            int kk = (t & 7) << 2;
            int grow = row0 + rr;
            float4 v = make_float4(0.f, 0.f, 0.f, 0.f);
            if (grow < NN)
                v = *reinterpret_cast<const float4*>(A + (size_t)grow * 128 + k0 + kk);
            sA[(kk + 0) * 68 + rr] = v.x;
            sA[(kk + 1) * 68 + rr] = v.y;
            sA[(kk + 2) * 68 + rr] = v.z;
            sA[(kk + 3) * 68 + rr] = v.w;
        }
#pragma unroll
        for (int t = tid; t < 1024; t += 256) {
            *reinterpret_cast<float4*>(&sW[t * 4]) =
                *reinterpret_cast<const float4*>(W + (size_t)k0 * 128 + t * 4);
        }
        __syncthreads();
#pragma unroll
        for (int k = 0; k < 32; ++k) {
            float4 av = *reinterpret_cast<const float4*>(&sA[k * 68 + ty * 4]);
            float4 w0 = *reinterpret_cast<const float4*>(&sW[k * 128 + tx * 8]);
            float4 w1 = *reinterpret_cast<const float4*>(&sW[k * 128 + tx * 8 + 4]);
            float a[4] = {av.x, av.y, av.z, av.w};
            float wv[8] = {w0.x, w0.y, w0.z, w0.w, w1.x, w1.y, w1.z, w1.w};
#pragma unroll
            for (int i = 0; i < 4; ++i)
#pragma unroll
                for (int j = 0; j < 8; ++j)
                    acc[i][j] = fmaf(a[i], wv[j], acc[i][j]);
        }
    }
    float4 bv0 = *reinterpret_cast<const float4*>(bias + tx * 8);
    float4 bv1 = *reinterpret_cast<const float4*>(bias + tx * 8 + 4);
#pragma unroll
    for (int i = 0; i < 4; ++i) {
        int grow = row0 + ty * 4 + i;
        if (grow < NN) {
            float* hp = H + (size_t)grow * 128 + tx * 8;
            float4 h0, h1v;
            if (STORE) {
                h0 = bv0; h1v = bv1;
            } else {
                h0 = *reinterpret_cast<float4*>(hp);
                h1v = *reinterpret_cast<float4*>(hp + 4);
                h0.x += bv0.x; h0.y += bv0.y; h0.z += bv0.z; h0.w += bv0.w;
                h1v.x += bv1.x; h1v.y += bv1.y; h1v.z += bv1.z; h1v.w += bv1.w;
            }
            h0.x += acc[i][0]; h0.y += acc[i][1]; h0.z += acc[i][2]; h0.w += acc[i][3];
            h1v.x += acc[i][4]; h1v.y += acc[i][5]; h1v.z += acc[i][6]; h1v.w += acc[i][7];
            *reinterpret_cast<float4*>(hp) = h0;
            *reinterpret_cast<float4*>(hp + 4) = h1v;
        }
    }
}

// ---------------- classifier: out = relu(H) @ Wc + bc -----------------------
__global__ __launch_bounds__(256) void k_classifier(const float* __restrict__ H,
                                                    const float* __restrict__ Wc,
                                                    const float* __restrict__ bc,
                                                    float* __restrict__ out) {
    __shared__ float sW[128 * 16];
    __shared__ float sb[16];
    int tid = threadIdx.x;
#pragma unroll
    for (int i = tid; i < 2048; i += 256) sW[i] = Wc[i];
    if (tid < 16) sb[tid] = bc[tid];
    __syncthreads();
    int node = blockIdx.x * 64 + (tid >> 2);
    if (node >= 3 * NN) return;
    int cg = (tid & 3) << 2;
    const float* h = H + (size_t)node * 128;
    float acc0 = 0.f, acc1 = 0.f, acc2 = 0.f, acc3 = 0.f;
#pragma unroll 4
    for (int k0 = 0; k0 < 128; k0 += 4) {
        float4 a4 = *reinterpret_cast<const float4*>(h + k0);
        float a;
        a = fmaxf(a4.x, 0.f);
        { float4 wv = *reinterpret_cast<const float4*>(&sW[(k0 + 0) * 16 + cg]);
          acc0 = fmaf(a, wv.x, acc0); acc1 = fmaf(a, wv.y, acc1);
          acc2 = fmaf(a, wv.z, acc2); acc3 = fmaf(a, wv.w, acc3); }
        a = fmaxf(a4.y, 0.f);
        { float4 wv = *reinterpret_cast<const float4*>(&sW[(k0 + 1) * 16 + cg]);
          acc0 = fmaf(a, wv.x, acc0); acc1 = fmaf(a, wv.y, acc1);
          acc2 = fmaf(a, wv.z, acc2); acc3 = fmaf(a, wv.w, acc3); }
        a = fmaxf(a4.z, 0.f);
        { float4 wv = *reinterpret_cast<const float4*>(&sW[(k0 + 2) * 16 + cg]);
          acc0 = fmaf(a, wv.x, acc0); acc1 = fmaf(a, wv.y, acc1);
          acc2 = fmaf(a, wv.z, acc2); acc3 = fmaf(a, wv.w, acc3); }
        a = fmaxf(a4.w, 0.f);
        { float4 wv = *reinterpret_cast<const float4*>(&sW[(k0 + 3) * 16 + cg]);
          acc0 = fmaf(a, wv.x, acc0); acc1 = fmaf(a, wv.y, acc1);
          acc2 = fmaf(a, wv.z, acc2); acc3 = fmaf(a, wv.w, acc3); }
    }
    float4 o = make_float4(acc0 + sb[cg], acc1 + sb[cg + 1],
                           acc2 + sb[cg + 2], acc3 + sb[cg + 3]);
    *reinterpret_cast<float4*>(out + (size_t)node * 16 + cg) = o;
}

// ---------------------------------------------------------------------------
extern "C" void kernel_launch(void* const* d_in, const int* in_sizes, int n_in,
                              void* d_out, int out_size, void* d_ws, size_t ws_size,
                              hipStream_t stream) {
    const float* x0 = (const float*)d_in[0];
    const float* x1 = (const float*)d_in[1];
    const float* x2 = (const float*)d_in[2];
    const float* W1 = (const float*)d_in[3];
    const float* b1 = (const float*)d_in[4];
    const float* W2 = (const float*)d_in[5];
    const float* b2 = (const float*)d_in[6];
    const float* Wc = (const float*)d_in[7];
    const float* bc = (const float*)d_in[8];
    const int* edges = (const int*)d_in[9];
    const float* x[3] = {x0, x1, x2};

    const int REL_S[9] = {0, 1, 1, 0, 2, 2, 0, 2, 1};
    const int REL_D[9] = {2, 2, 0, 0, 1, 0, 0, 2, 1};
    // execution order: first relation per dst type (STORE epilogue) up front
    const int ORDER[9] = {2, 4, 0, 3, 5, 6, 8, 1, 7};

    // ---- workspace carve-up with overlays (~199 MB peak) ----
    char* p = (char*)d_ws;
    auto alloc = [&](size_t bytes) -> void* {
        void* r = (void*)p;
        p += (bytes + 255) & ~(size_t)255;
        return r;
    };
    float* h2 = (float*)alloc((size_t)3 * NN * 128 * sizeof(float));  // 76.8 MB
    unsigned* hist = (unsigned*)h2;    // alias: hist dead after k_sums
    float* h1 = (float*)alloc((size_t)3 * NN * 128 * sizeof(float));  // 76.8 MB
    int* cur = (int*)h1;               // alias: cur dead after k_fill
    int* deg_d = (int*)(h1 + 9 * NN);  // alias: deg_d dead after k_offsets
    float* Abuf = (float*)alloc((size_t)NN * 128 * sizeof(float));    // 25.6 MB
    int* off = (int*)alloc((size_t)9 * (NN + 1) * sizeof(int));
    float* ns = (float*)alloc((size_t)9 * NN * sizeof(float));        // live all layers
    float* nd = (float*)alloc((size_t)9 * NN * sizeof(float));
    int* esrc = (int*)alloc((size_t)9 * EE * sizeof(int));            // 14.4 MB

    // ---- CSR build (reused by both layers) ----
    k_hist<<<288, 256, 0, stream>>>(edges, hist);
    k_sums<<<(9 * (NN / 2) + 255) / 256, 256, 0, stream>>>(hist, ns, nd, deg_d);
    k_offsets<<<9, 256, 0, stream>>>(deg_d, off, cur);
    k_fill<<<(9 * EE + 255) / 256, 256, 0, stream>>>(edges, cur, esrc);

    const int agg_blocks = (NN * 64) / 256;   // 12500
    const int gemm_blocks = (NN + 63) / 64;   // 782

    // ---- layer 1 ----
    for (int i = 0; i < 9; ++i) {
        int r = ORDER[i];
        int s = REL_S[r], d = REL_D[r];
        k_agg<0><<<agg_blocks, 256, 0, stream>>>(x[s], off + r * (NN + 1),
                                                 esrc + (size_t)r * EE,
                                                 ns + r * NN, nd + r * NN, Abuf);
        if (i < 3)
            k_gemm<1><<<gemm_blocks, 256, 0, stream>>>(
                Abuf, W1 + (size_t)r * 128 * 128, b1 + (size_t)r * 128,
                h1 + (size_t)d * NN * 128);
        else
            k_gemm<0><<<gemm_blocks, 256, 0, stream>>>(
                Abuf, W1 + (size_t)r * 128 * 128, b1 + (size_t)r * 128,
                h1 + (size_t)d * NN * 128);
    }

    // ---- layer 2 (input = relu(h1), folded into gather) ----
    for (int i = 0; i < 9; ++i) {
        int r = ORDER[i];
        int s = REL_S[r], d = REL_D[r];
        k_agg<1><<<agg_blocks, 256, 0, stream>>>(h1 + (size_t)s * NN * 128,
                                                 off + r * (NN + 1),
                                                 esrc + (size_t)r * EE,
                                                 ns + r * NN, nd + r * NN, Abuf);
        if (i < 3)
            k_gemm<1><<<gemm_blocks, 256, 0, stream>>>(
                Abuf, W2 + (size_t)r * 128 * 128, b2 + (size_t)r * 128,
                h2 + (size_t)d * NN * 128);
        else
            k_gemm<0><<<gemm_blocks, 256, 0, stream>>>(
                Abuf, W2 + (size_t)r * 128 * 128, b2 + (size_t)r * 128,
                h2 + (size_t)d * NN * 128);
    }

    // ---- classifier: out = relu(h2) @ Wc + bc ----
    k_classifier<<<(3 * NN + 63) / 64, 256, 0, stream>>>(h2, Wc, bc, (float*)d_out);
}

// Round 5
// 1639.229 us; speedup vs baseline: 3.0293x; 1.0067x over previous
//
#include <hip/hip_runtime.h>
#include <hip/hip_bf16.h>

// ---------------------------------------------------------------------------
// Hetero-GCN (3 node types, 9 relations), 2 GraphConv layers + classifier.
// Round 5:
//  - k_fill: nontemporal scatter stores (write traffic is line-granular:
//    203MB for 14.4MB useful regardless of payload size; NT should bypass
//    line allocation).
//  - GEMMs pair-merged per dst type (K=256, 2 A-slices): 18 -> 10 dispatches,
//    epilogue H traffic 384 -> 179 MB/layer.
//  - agg launches pair-batched via gridDim.y: 18 -> 10 dispatches.
// All fp32.
// ---------------------------------------------------------------------------

#define NN 50000
#define EE 400000
#define NRG 2            // node ranges for histogram
#define RGN (NN / NRG)   // 25000 nodes per range
#define HCH 8            // edge chunks
#define HEG (EE / HCH)   // 50000 edges per chunk

// ---------------- degree histogram (chunked, LDS, no global atomics) --------
__global__ __launch_bounds__(256) void k_hist(const int* __restrict__ edges,
                                              unsigned* __restrict__ hist) {
    __shared__ unsigned bins[RGN / 2];  // 12500 u32 = 50 KB
    int bid = blockIdx.x;
    int task = bid >> 4;           // r*2 + side
    int rem = bid & 15;
    int rg = rem >> 3;
    int c = rem & 7;
    int r = task >> 1, side = task & 1;
    int tid = threadIdx.x;
    for (int i = tid; i < RGN / 2; i += 256) bins[i] = 0;
    __syncthreads();
    const int* ea = edges + (size_t)r * 2 * EE + (size_t)side * EE + (size_t)c * HEG;
    int base = rg * RGN;
    for (int e = tid; e < HEG; e += 256) {
        int idx = __builtin_nontemporal_load(&ea[e]) - base;
        if ((unsigned)idx < (unsigned)RGN)
            atomicAdd(&bins[idx >> 1], (idx & 1) ? 65536u : 1u);
    }
    __syncthreads();
    unsigned* ho = hist + ((size_t)(task * NRG + rg) * HCH + c) * (RGN / 2);
    for (int i = tid; i < RGN / 2; i += 256) ho[i] = bins[i];
}

// ---------------- reduce histograms -> ns, nd, deg_d ------------------------
__global__ void k_sums(const unsigned* __restrict__ hist, float* __restrict__ ns,
                       float* __restrict__ nd, int* __restrict__ deg_d) {
    int i = blockIdx.x * blockDim.x + threadIdx.x;
    if (i >= 9 * (NN / 2)) return;
    int r = i / (NN / 2);
    int ps = i - r * (NN / 2);        // node-pair slot within relation
    int rg = ps / (RGN / 2);
    int slot = ps - rg * (RGN / 2);
    const unsigned* hs = hist + ((size_t)((r * 2 + 0) * NRG + rg) * HCH) * (RGN / 2) + slot;
    const unsigned* hd = hist + ((size_t)((r * 2 + 1) * NRG + rg) * HCH) * (RGN / 2) + slot;
    unsigned slo = 0, shi = 0, dlo = 0, dhi = 0;
#pragma unroll
    for (int c = 0; c < HCH; ++c) {
        unsigned a = hs[(size_t)c * (RGN / 2)];
        unsigned b = hd[(size_t)c * (RGN / 2)];
        slo += a & 0xffffu; shi += a >> 16;
        dlo += b & 0xffffu; dhi += b >> 16;
    }
    int n0 = 2 * ps;
    ns[r * NN + n0]     = slo ? rsqrtf((float)slo) : 0.f;
    ns[r * NN + n0 + 1] = shi ? rsqrtf((float)shi) : 0.f;
    nd[r * NN + n0]     = dlo ? rsqrtf((float)dlo) : 0.f;
    nd[r * NN + n0 + 1] = dhi ? rsqrtf((float)dhi) : 0.f;
    deg_d[r * NN + n0]     = (int)dlo;
    deg_d[r * NN + n0 + 1] = (int)dhi;
}

// ---------------- exclusive scan of in-degrees -> CSR offsets ---------------
__global__ __launch_bounds__(256) void k_offsets(const int* __restrict__ deg_d,
                                                 int* __restrict__ off,
                                                 int* __restrict__ cur) {
    __shared__ int wsum[4];
    __shared__ int s_carry;
    int r = blockIdx.x;
    const int* c = deg_d + r * NN;
    int* o = off + r * (NN + 1);
    int* cu = cur + r * NN;
    int tid = threadIdx.x, lane = tid & 63, w = tid >> 6;
    if (tid == 0) s_carry = 0;
    __syncthreads();
    for (int base = 0; base < NN; base += 256) {
        int i = base + tid;
        int v = (i < NN) ? c[i] : 0;
        int x = v;
#pragma unroll
        for (int s = 1; s < 64; s <<= 1) {
            int y = __shfl_up(x, (unsigned)s);
            if (lane >= s) x += y;
        }
        if (lane == 63) wsum[w] = x;
        __syncthreads();
        int wbase = 0;
#pragma unroll
        for (int j = 0; j < 3; ++j) wbase += (j < w) ? wsum[j] : 0;
        int excl = s_carry + wbase + x - v;
        if (i < NN) { o[i] = excl; cu[i] = excl; }
        __syncthreads();
        if (tid == 255) s_carry += wbase + x;
    }
    __syncthreads();
    if (tid == 0) o[NN] = s_carry;
}

// ---------------- CSR fill (global atomics, NT scatter stores) --------------
__global__ __launch_bounds__(256) void k_fill(const int* __restrict__ edges,
                                              int* __restrict__ cur,
                                              int* __restrict__ esrc) {
    int i = blockIdx.x * blockDim.x + threadIdx.x;
    if (i >= 9 * EE) return;
    int r = i / EE;
    int e = i - r * EE;
    int src = __builtin_nontemporal_load(&edges[(size_t)r * 2 * EE + e]);
    int dst = __builtin_nontemporal_load(&edges[(size_t)r * 2 * EE + EE + e]);
    int pos = atomicAdd(&cur[r * NN + dst], 1);
    __builtin_nontemporal_store(src, &esrc[(size_t)r * EE + pos]);
}

// ---------------- aggregation (CSR gather, one wave per dst row) ------------
// Batched: gridDim.y selects task (one relation each). 4-way unrolled ILP.
struct AggT {
    const float* xin;
    const int* off;
    const int* esrc;
    const float* ns;
    const float* nd;
    float* A;
};

template <int RELU>
__global__ __launch_bounds__(256) void k_agg2(AggT ta, AggT tb) {
    AggT t = (blockIdx.y == 0) ? ta : tb;
    int wave = (blockIdx.x * blockDim.x + threadIdx.x) >> 6;
    int lane = threadIdx.x & 63;
    if (wave >= NN) return;
    int e0 = t.off[wave], e1 = t.off[wave + 1];
    const float* xin = t.xin;
    const int* esrc = t.esrc;
    const float* ns = t.ns;
    float a0 = 0.f, a1 = 0.f, b0 = 0.f, b1 = 0.f;
    float c0 = 0.f, c1 = 0.f, d0 = 0.f, d1 = 0.f;
    int e = e0;
    for (; e + 4 <= e1; e += 4) {
        int s0 = esrc[e], s1 = esrc[e + 1], s2 = esrc[e + 2], s3 = esrc[e + 3];
        float w0 = ns[s0], w1 = ns[s1], w2 = ns[s2], w3 = ns[s3];
        float2 v0 = *reinterpret_cast<const float2*>(xin + (size_t)s0 * 128 + lane * 2);
        float2 v1 = *reinterpret_cast<const float2*>(xin + (size_t)s1 * 128 + lane * 2);
        float2 v2 = *reinterpret_cast<const float2*>(xin + (size_t)s2 * 128 + lane * 2);
        float2 v3 = *reinterpret_cast<const float2*>(xin + (size_t)s3 * 128 + lane * 2);
        if (RELU) {
            v0.x = fmaxf(v0.x, 0.f); v0.y = fmaxf(v0.y, 0.f);
            v1.x = fmaxf(v1.x, 0.f); v1.y = fmaxf(v1.y, 0.f);
            v2.x = fmaxf(v2.x, 0.f); v2.y = fmaxf(v2.y, 0.f);
            v3.x = fmaxf(v3.x, 0.f); v3.y = fmaxf(v3.y, 0.f);
        }
        a0 = fmaf(w0, v0.x, a0); a1 = fmaf(w0, v0.y, a1);
        b0 = fmaf(w1, v1.x, b0); b1 = fmaf(w1, v1.y, b1);
        c0 = fmaf(w2, v2.x, c0); c1 = fmaf(w2, v2.y, c1);
        d0 = fmaf(w3, v3.x, d0); d1 = fmaf(w3, v3.y, d1);
    }
    for (; e < e1; ++e) {
        int s = esrc[e];
        float w = ns[s];
        float2 v = *reinterpret_cast<const float2*>(xin + (size_t)s * 128 + lane * 2);
        if (RELU) { v.x = fmaxf(v.x, 0.f); v.y = fmaxf(v.y, 0.f); }
        a0 = fmaf(w, v.x, a0); a1 = fmaf(w, v.y, a1);
    }
    float nr = t.nd[wave];
    float2 o = make_float2(((a0 + b0) + (c0 + d0)) * nr,
                           ((a1 + b1) + (c1 + d1)) * nr);
    *reinterpret_cast<float2*>(t.A + (size_t)wave * 128 + lane * 2) = o;
}

// ---------------- GEMM: H (=|+=) [A0|A1] @ [Wa;Wb] + ba (+bb) ---------------
// NS slices of A ([NS][NN][128]); K = NS*128. STORE=1 overwrites H.
template <int NS, int STORE>
__global__ __launch_bounds__(256) void k_gemmN(const float* __restrict__ A,
                                               const float* __restrict__ Wa,
                                               const float* __restrict__ Wb,
                                               const float* __restrict__ ba,
                                               const float* __restrict__ bb,
                                               float* __restrict__ H) {
    __shared__ float sA[32 * 68];   // [k][row], padded stride 68
    __shared__ float sW[32 * 128];  // [k][col]
    int tid = threadIdx.x;
    int row0 = blockIdx.x * 64;
    int tx = tid & 15;   // col group: cols tx*8 .. tx*8+7
    int ty = tid >> 4;   // row group: rows ty*4 .. ty*4+3
    float acc[4][8] = {};
#pragma unroll
    for (int s = 0; s < NS; ++s) {
        const float* W = (s == 0) ? Wa : Wb;
        const float* As = A + (size_t)s * NN * 128;
        for (int k0 = 0; k0 < 128; k0 += 32) {
            __syncthreads();
#pragma unroll
            for (int t = tid; t < 512; t += 256) {
                int rr = t >> 3;
                int kk = (t & 7) << 2;
                int grow = row0 + rr;
                float4 v = make_float4(0.f, 0.f, 0.f, 0.f);
                if (grow < NN)
                    v = *reinterpret_cast<const float4*>(As + (size_t)grow * 128 + k0 + kk);
                sA[(kk + 0) * 68 + rr] = v.x;
                sA[(kk + 1) * 68 + rr] = v.y;
                sA[(kk + 2) * 68 + rr] = v.z;
                sA[(kk + 3) * 68 + rr] = v.w;
            }
#pragma unroll
            for (int t = tid; t < 1024; t += 256) {
                *reinterpret_cast<float4*>(&sW[t * 4]) =
                    *reinterpret_cast<const float4*>(W + (size_t)k0 * 128 + t * 4);
            }
            __syncthreads();
#pragma unroll
            for (int k = 0; k < 32; ++k) {
                float4 av = *reinterpret_cast<const float4*>(&sA[k * 68 + ty * 4]);
                float4 w0 = *reinterpret_cast<const float4*>(&sW[k * 128 + tx * 8]);
                float4 w1 = *reinterpret_cast<const float4*>(&sW[k * 128 + tx * 8 + 4]);
                float a[4] = {av.x, av.y, av.z, av.w};
                float wv[8] = {w0.x, w0.y, w0.z, w0.w, w1.x, w1.y, w1.z, w1.w};
#pragma unroll
                for (int i = 0; i < 4; ++i)
#pragma unroll
                    for (int j = 0; j < 8; ++j)
                        acc[i][j] = fmaf(a[i], wv[j], acc[i][j]);
            }
        }
    }
    float4 bv0 = *reinterpret_cast<const float4*>(ba + tx * 8);
    float4 bv1 = *reinterpret_cast<const float4*>(ba + tx * 8 + 4);
    if (NS == 2) {
        float4 c0 = *reinterpret_cast<const float4*>(bb + tx * 8);
        float4 c1 = *reinterpret_cast<const float4*>(bb + tx * 8 + 4);
        bv0.x += c0.x; bv0.y += c0.y; bv0.z += c0.z; bv0.w += c0.w;
        bv1.x += c1.x; bv1.y += c1.y; bv1.z += c1.z; bv1.w += c1.w;
    }
#pragma unroll
    for (int i = 0; i < 4; ++i) {
        int grow = row0 + ty * 4 + i;
        if (grow < NN) {
            float* hp = H + (size_t)grow * 128 + tx * 8;
            float4 h0, h1v;
            if (STORE) {
                h0 = bv0; h1v = bv1;
            } else {
                h0 = *reinterpret_cast<float4*>(hp);
                h1v = *reinterpret_cast<float4*>(hp + 4);
                h0.x += bv0.x; h0.y += bv0.y; h0.z += bv0.z; h0.w += bv0.w;
                h1v.x += bv1.x; h1v.y += bv1.y; h1v.z += bv1.z; h1v.w += bv1.w;
            }
            h0.x += acc[i][0]; h0.y += acc[i][1]; h0.z += acc[i][2]; h0.w += acc[i][3];
            h1v.x += acc[i][4]; h1v.y += acc[i][5]; h1v.z += acc[i][6]; h1v.w += acc[i][7];
            *reinterpret_cast<float4*>(hp) = h0;
            *reinterpret_cast<float4*>(hp + 4) = h1v;
        }
    }
}

// ---------------- classifier: out = relu(H) @ Wc + bc -----------------------
__global__ __launch_bounds__(256) void k_classifier(const float* __restrict__ H,
                                                    const float* __restrict__ Wc,
                                                    const float* __restrict__ bc,
                                                    float* __restrict__ out) {
    __shared__ float sW[128 * 16];
    __shared__ float sb[16];
    int tid = threadIdx.x;
#pragma unroll
    for (int i = tid; i < 2048; i += 256) sW[i] = Wc[i];
    if (tid < 16) sb[tid] = bc[tid];
    __syncthreads();
    int node = blockIdx.x * 64 + (tid >> 2);
    if (node >= 3 * NN) return;
    int cg = (tid & 3) << 2;
    const float* h = H + (size_t)node * 128;
    float acc0 = 0.f, acc1 = 0.f, acc2 = 0.f, acc3 = 0.f;
#pragma unroll 4
    for (int k0 = 0; k0 < 128; k0 += 4) {
        float4 a4 = *reinterpret_cast<const float4*>(h + k0);
        float a;
        a = fmaxf(a4.x, 0.f);
        { float4 wv = *reinterpret_cast<const float4*>(&sW[(k0 + 0) * 16 + cg]);
          acc0 = fmaf(a, wv.x, acc0); acc1 = fmaf(a, wv.y, acc1);
          acc2 = fmaf(a, wv.z, acc2); acc3 = fmaf(a, wv.w, acc3); }
        a = fmaxf(a4.y, 0.f);
        { float4 wv = *reinterpret_cast<const float4*>(&sW[(k0 + 1) * 16 + cg]);
          acc0 = fmaf(a, wv.x, acc0); acc1 = fmaf(a, wv.y, acc1);
          acc2 = fmaf(a, wv.z, acc2); acc3 = fmaf(a, wv.w, acc3); }
        a = fmaxf(a4.z, 0.f);
        { float4 wv = *reinterpret_cast<const float4*>(&sW[(k0 + 2) * 16 + cg]);
          acc0 = fmaf(a, wv.x, acc0); acc1 = fmaf(a, wv.y, acc1);
          acc2 = fmaf(a, wv.z, acc2); acc3 = fmaf(a, wv.w, acc3); }
        a = fmaxf(a4.w, 0.f);
        { float4 wv = *reinterpret_cast<const float4*>(&sW[(k0 + 3) * 16 + cg]);
          acc0 = fmaf(a, wv.x, acc0); acc1 = fmaf(a, wv.y, acc1);
          acc2 = fmaf(a, wv.z, acc2); acc3 = fmaf(a, wv.w, acc3); }
    }
    float4 o = make_float4(acc0 + sb[cg], acc1 + sb[cg + 1],
                           acc2 + sb[cg + 2], acc3 + sb[cg + 3]);
    *reinterpret_cast<float4*>(out + (size_t)node * 16 + cg) = o;
}

// ---------------------------------------------------------------------------
extern "C" void kernel_launch(void* const* d_in, const int* in_sizes, int n_in,
                              void* d_out, int out_size, void* d_ws, size_t ws_size,
                              hipStream_t stream) {
    const float* x0 = (const float*)d_in[0];
    const float* x1 = (const float*)d_in[1];
    const float* x2 = (const float*)d_in[2];
    const float* W1 = (const float*)d_in[3];
    const float* b1 = (const float*)d_in[4];
    const float* W2 = (const float*)d_in[5];
    const float* b2 = (const float*)d_in[6];
    const float* Wc = (const float*)d_in[7];
    const float* bc = (const float*)d_in[8];
    const int* edges = (const int*)d_in[9];
    const float* x[3] = {x0, x1, x2};

    const int REL_S[9] = {0, 1, 1, 0, 2, 2, 0, 2, 1};

    // ---- workspace carve-up with overlays (~225 MB peak) ----
    char* p = (char*)d_ws;
    auto alloc = [&](size_t bytes) -> void* {
        void* r = (void*)p;
        p += (bytes + 255) & ~(size_t)255;
        return r;
    };
    float* h2 = (float*)alloc((size_t)3 * NN * 128 * sizeof(float));  // 76.8 MB
    unsigned* hist = (unsigned*)h2;    // alias: hist dead after k_sums
    float* h1 = (float*)alloc((size_t)3 * NN * 128 * sizeof(float));  // 76.8 MB
    int* cur = (int*)h1;               // alias: cur dead after k_fill
    int* deg_d = (int*)(h1 + 9 * NN);  // alias: deg_d dead after k_offsets
    float* A2 = (float*)alloc((size_t)2 * NN * 128 * sizeof(float));  // 51.2 MB
    int* off = (int*)alloc((size_t)9 * (NN + 1) * sizeof(int));
    float* ns = (float*)alloc((size_t)9 * NN * sizeof(float));
    float* nd = (float*)alloc((size_t)9 * NN * sizeof(float));
    int* esrc = (int*)alloc((size_t)9 * EE * sizeof(int));            // 14.4 MB
    float* A0 = A2;
    float* A1 = A2 + (size_t)NN * 128;

    // ---- CSR build (reused by both layers) ----
    k_hist<<<288, 256, 0, stream>>>(edges, hist);
    k_sums<<<(9 * (NN / 2) + 255) / 256, 256, 0, stream>>>(hist, ns, nd, deg_d);
    k_offsets<<<9, 256, 0, stream>>>(deg_d, off, cur);
    k_fill<<<(9 * EE + 255) / 256, 256, 0, stream>>>(edges, cur, esrc);

    const dim3 agg2_grid(12500, 2);
    const dim3 agg1_grid(12500, 1);
    const int gemm_blocks = (NN + 63) / 64;   // 782

    auto mk = [&](int r, const float* xin, float* Aslot) -> AggT {
        return AggT{xin, off + r * (NN + 1), esrc + (size_t)r * EE,
                    ns + r * NN, nd + r * NN, Aslot};
    };

    // ======== layer 1 (inputs x[], no relu) ========
    {
        const float* W = W1; const float* b = b1; float* h = h1;
        // dst0: rels (2,3) STORE, (5,6) ACCUM
        k_agg2<0><<<agg2_grid, 256, 0, stream>>>(mk(2, x[REL_S[2]], A0), mk(3, x[REL_S[3]], A1));
        k_gemmN<2, 1><<<gemm_blocks, 256, 0, stream>>>(
            A2, W + 2 * 16384, W + 3 * 16384, b + 2 * 128, b + 3 * 128, h + (size_t)0 * NN * 128);
        k_agg2<0><<<agg2_grid, 256, 0, stream>>>(mk(5, x[REL_S[5]], A0), mk(6, x[REL_S[6]], A1));
        k_gemmN<2, 0><<<gemm_blocks, 256, 0, stream>>>(
            A2, W + 5 * 16384, W + 6 * 16384, b + 5 * 128, b + 6 * 128, h + (size_t)0 * NN * 128);
        // dst1: rels (4,8) STORE
        k_agg2<0><<<agg2_grid, 256, 0, stream>>>(mk(4, x[REL_S[4]], A0), mk(8, x[REL_S[8]], A1));
        k_gemmN<2, 1><<<gemm_blocks, 256, 0, stream>>>(
            A2, W + 4 * 16384, W + 8 * 16384, b + 4 * 128, b + 8 * 128, h + (size_t)1 * NN * 128);
        // dst2: rels (0,1) STORE, (7) ACCUM
        k_agg2<0><<<agg2_grid, 256, 0, stream>>>(mk(0, x[REL_S[0]], A0), mk(1, x[REL_S[1]], A1));
        k_gemmN<2, 1><<<gemm_blocks, 256, 0, stream>>>(
            A2, W + 0 * 16384, W + 1 * 16384, b + 0 * 128, b + 1 * 128, h + (size_t)2 * NN * 128);
        k_agg2<0><<<agg1_grid, 256, 0, stream>>>(mk(7, x[REL_S[7]], A0), mk(7, x[REL_S[7]], A0));
        k_gemmN<1, 0><<<gemm_blocks, 256, 0, stream>>>(
            A2, W + 7 * 16384, W + 7 * 16384, b + 7 * 128, b + 7 * 128, h + (size_t)2 * NN * 128);
    }

    // ======== layer 2 (inputs relu(h1), folded into gather) ========
    {
        const float* W = W2; const float* b = b2; float* h = h2;
        auto hin = [&](int r) { return h1 + (size_t)REL_S[r] * NN * 128; };
        k_agg2<1><<<agg2_grid, 256, 0, stream>>>(mk(2, hin(2), A0), mk(3, hin(3), A1));
        k_gemmN<2, 1><<<gemm_blocks, 256, 0, stream>>>(
            A2, W + 2 * 16384, W + 3 * 16384, b + 2 * 128, b + 3 * 128, h + (size_t)0 * NN * 128);
        k_agg2<1><<<agg2_grid, 256, 0, stream>>>(mk(5, hin(5), A0), mk(6, hin(6), A1));
        k_gemmN<2, 0><<<gemm_blocks, 256, 0, stream>>>(
            A2, W + 5 * 16384, W + 6 * 16384, b + 5 * 128, b + 6 * 128, h + (size_t)0 * NN * 128);
        k_agg2<1><<<agg2_grid, 256, 0, stream>>>(mk(4, hin(4), A0), mk(8, hin(8), A1));
        k_gemmN<2, 1><<<gemm_blocks, 256, 0, stream>>>(
            A2, W + 4 * 16384, W + 8 * 16384, b + 4 * 128, b + 8 * 128, h + (size_t)1 * NN * 128);
        k_agg2<1><<<agg2_grid, 256, 0, stream>>>(mk(0, hin(0), A0), mk(1, hin(1), A1));
        k_gemmN<2, 1><<<gemm_blocks, 256, 0, stream>>>(
            A2, W + 0 * 16384, W + 1 * 16384, b + 0 * 128, b + 1 * 128, h + (size_t)2 * NN * 128);
        k_agg2<1><<<agg1_grid, 256, 0, stream>>>(mk(7, hin(7), A0), mk(7, hin(7), A0));
        k_gemmN<1, 0><<<gemm_blocks, 256, 0, stream>>>(
            A2, W + 7 * 16384, W + 7 * 16384, b + 7 * 128, b + 7 * 128, h + (size_t)2 * NN * 128);
    }

    // ---- classifier: out = relu(h2) @ Wc + bc ----
    k_classifier<<<(3 * NN + 63) / 64, 256, 0, stream>>>(h2, Wc, bc, (float*)d_out);
}

// Round 6
// 1429.397 us; speedup vs baseline: 3.4740x; 1.1468x over previous
//
#include <hip/hip_runtime.h>
#include <hip/hip_bf16.h>

// ---------------------------------------------------------------------------
// Hetero-GCN (3 node types, 9 relations), 2 GraphConv layers + classifier.
// Round 6:
//  - GEMM moved to matrix cores: 3-pass split-bf16 (A_hi*W_hi + A_hi*W_lo +
//    A_lo*W_hi), mfma_f32_16x16x32_bf16, fp32 accumulate. No LDS: A planes
//    row-major bf16 -> fragment = one 16B global load (L2-resident); W
//    pre-converted to chunk-major [4][128][32] bf16 planes by k_wprep.
//  - k_agg2 emits bf16 hi/lo planes directly (same write bytes as fp32).
//  - k_fill: NT store reverted (round-5: +63us, WRITE_SIZE up — NT defeats
//    L2 line-merging on random scatter).
// ---------------------------------------------------------------------------

#define NN 50000
#define EE 400000
#define NRG 2            // node ranges for histogram
#define RGN (NN / NRG)   // 25000 nodes per range
#define HCH 8            // edge chunks
#define HEG (EE / HCH)   // 50000 edges per chunk

typedef __attribute__((ext_vector_type(8))) short bf16x8;
typedef __attribute__((ext_vector_type(4))) float f32x4;
#define MFMA16(a, b, c) __builtin_amdgcn_mfma_f32_16x16x32_bf16(a, b, c, 0, 0, 0)

// ---------------- degree histogram (chunked, LDS, no global atomics) --------
__global__ __launch_bounds__(256) void k_hist(const int* __restrict__ edges,
                                              unsigned* __restrict__ hist) {
    __shared__ unsigned bins[RGN / 2];  // 12500 u32 = 50 KB
    int bid = blockIdx.x;
    int task = bid >> 4;           // r*2 + side
    int rem = bid & 15;
    int rg = rem >> 3;
    int c = rem & 7;
    int r = task >> 1, side = task & 1;
    int tid = threadIdx.x;
    for (int i = tid; i < RGN / 2; i += 256) bins[i] = 0;
    __syncthreads();
    const int* ea = edges + (size_t)r * 2 * EE + (size_t)side * EE + (size_t)c * HEG;
    int base = rg * RGN;
    for (int e = tid; e < HEG; e += 256) {
        int idx = __builtin_nontemporal_load(&ea[e]) - base;
        if ((unsigned)idx < (unsigned)RGN)
            atomicAdd(&bins[idx >> 1], (idx & 1) ? 65536u : 1u);
    }
    __syncthreads();
    unsigned* ho = hist + ((size_t)(task * NRG + rg) * HCH + c) * (RGN / 2);
    for (int i = tid; i < RGN / 2; i += 256) ho[i] = bins[i];
}

// ---------------- reduce histograms -> ns, nd, deg_d ------------------------
__global__ void k_sums(const unsigned* __restrict__ hist, float* __restrict__ ns,
                       float* __restrict__ nd, int* __restrict__ deg_d) {
    int i = blockIdx.x * blockDim.x + threadIdx.x;
    if (i >= 9 * (NN / 2)) return;
    int r = i / (NN / 2);
    int ps = i - r * (NN / 2);
    int rg = ps / (RGN / 2);
    int slot = ps - rg * (RGN / 2);
    const unsigned* hs = hist + ((size_t)((r * 2 + 0) * NRG + rg) * HCH) * (RGN / 2) + slot;
    const unsigned* hd = hist + ((size_t)((r * 2 + 1) * NRG + rg) * HCH) * (RGN / 2) + slot;
    unsigned slo = 0, shi = 0, dlo = 0, dhi = 0;
#pragma unroll
    for (int c = 0; c < HCH; ++c) {
        unsigned a = hs[(size_t)c * (RGN / 2)];
        unsigned b = hd[(size_t)c * (RGN / 2)];
        slo += a & 0xffffu; shi += a >> 16;
        dlo += b & 0xffffu; dhi += b >> 16;
    }
    int n0 = 2 * ps;
    ns[r * NN + n0]     = slo ? rsqrtf((float)slo) : 0.f;
    ns[r * NN + n0 + 1] = shi ? rsqrtf((float)shi) : 0.f;
    nd[r * NN + n0]     = dlo ? rsqrtf((float)dlo) : 0.f;
    nd[r * NN + n0 + 1] = dhi ? rsqrtf((float)dhi) : 0.f;
    deg_d[r * NN + n0]     = (int)dlo;
    deg_d[r * NN + n0 + 1] = (int)dhi;
}

// ---------------- exclusive scan of in-degrees -> CSR offsets ---------------
__global__ __launch_bounds__(256) void k_offsets(const int* __restrict__ deg_d,
                                                 int* __restrict__ off,
                                                 int* __restrict__ cur) {
    __shared__ int wsum[4];
    __shared__ int s_carry;
    int r = blockIdx.x;
    const int* c = deg_d + r * NN;
    int* o = off + r * (NN + 1);
    int* cu = cur + r * NN;
    int tid = threadIdx.x, lane = tid & 63, w = tid >> 6;
    if (tid == 0) s_carry = 0;
    __syncthreads();
    for (int base = 0; base < NN; base += 256) {
        int i = base + tid;
        int v = (i < NN) ? c[i] : 0;
        int x = v;
#pragma unroll
        for (int s = 1; s < 64; s <<= 1) {
            int y = __shfl_up(x, (unsigned)s);
            if (lane >= s) x += y;
        }
        if (lane == 63) wsum[w] = x;
        __syncthreads();
        int wbase = 0;
#pragma unroll
        for (int j = 0; j < 3; ++j) wbase += (j < w) ? wsum[j] : 0;
        int excl = s_carry + wbase + x - v;
        if (i < NN) { o[i] = excl; cu[i] = excl; }
        __syncthreads();
        if (tid == 255) s_carry += wbase + x;
    }
    __syncthreads();
    if (tid == 0) o[NN] = s_carry;
}

// ---------------- CSR fill (global atomics; plain store) --------------------
__global__ __launch_bounds__(256) void k_fill(const int* __restrict__ edges,
                                              int* __restrict__ cur,
                                              int* __restrict__ esrc) {
    int i = blockIdx.x * blockDim.x + threadIdx.x;
    if (i >= 9 * EE) return;
    int r = i / EE;
    int e = i - r * EE;
    int src = __builtin_nontemporal_load(&edges[(size_t)r * 2 * EE + e]);
    int dst = __builtin_nontemporal_load(&edges[(size_t)r * 2 * EE + EE + e]);
    int pos = atomicAdd(&cur[r * NN + dst], 1);
    esrc[(size_t)r * EE + pos] = src;
}

// ---------------- W prep: fp32 [K][N] -> chunk-major bf16 hi/lo planes ------
// out layout per (layer*9+r): [4 kchunks][128 n][32 k]
__global__ void k_wprep(const float* __restrict__ W1, const float* __restrict__ W2,
                        unsigned short* __restrict__ whi,
                        unsigned short* __restrict__ wlo) {
    int id = blockIdx.x * blockDim.x + threadIdx.x;
    const int total = 2 * 9 * 128 * 128;
    if (id >= total) return;
    int n = id & 127;
    int k = (id >> 7) & 127;
    int rl = id >> 14;  // layer*9 + r
    const float* W = (rl < 9) ? W1 : W2;
    int r = (rl < 9) ? rl : rl - 9;
    float f = W[((size_t)r * 128 + k) * 128 + n];
    unsigned u = __float_as_uint(f);
    unsigned hb = (u + 0x7fffu + ((u >> 16) & 1u)) & 0xffff0000u;
    float lo = f - __uint_as_float(hb);
    unsigned ul = __float_as_uint(lo);
    unsigned short l16 = (unsigned short)((ul + 0x7fffu + ((ul >> 16) & 1u)) >> 16);
    size_t oidx = (((size_t)rl * 4 + (k >> 5)) * 128 + n) * 32 + (k & 31);
    whi[oidx] = (unsigned short)(hb >> 16);
    wlo[oidx] = l16;
}

// ---------------- aggregation (CSR gather, one wave per dst row) ------------
// Emits bf16 hi/lo planes of the aggregated row.
struct AggT {
    const float* xin;
    const int* off;
    const int* esrc;
    const float* ns;
    const float* nd;
    unsigned short* Ah;
    unsigned short* Al;
};

template <int RELU>
__global__ __launch_bounds__(256) void k_agg2(AggT ta, AggT tb) {
    AggT t = (blockIdx.y == 0) ? ta : tb;
    int wave = (blockIdx.x * blockDim.x + threadIdx.x) >> 6;
    int lane = threadIdx.x & 63;
    if (wave >= NN) return;
    int e0 = t.off[wave], e1 = t.off[wave + 1];
    const float* xin = t.xin;
    const int* esrc = t.esrc;
    const float* ns = t.ns;
    float a0 = 0.f, a1 = 0.f, b0 = 0.f, b1 = 0.f;
    float c0 = 0.f, c1 = 0.f, d0 = 0.f, d1 = 0.f;
    int e = e0;
    for (; e + 4 <= e1; e += 4) {
        int s0 = esrc[e], s1 = esrc[e + 1], s2 = esrc[e + 2], s3 = esrc[e + 3];
        float w0 = ns[s0], w1 = ns[s1], w2 = ns[s2], w3 = ns[s3];
        float2 v0 = *reinterpret_cast<const float2*>(xin + (size_t)s0 * 128 + lane * 2);
        float2 v1 = *reinterpret_cast<const float2*>(xin + (size_t)s1 * 128 + lane * 2);
        float2 v2 = *reinterpret_cast<const float2*>(xin + (size_t)s2 * 128 + lane * 2);
        float2 v3 = *reinterpret_cast<const float2*>(xin + (size_t)s3 * 128 + lane * 2);
        if (RELU) {
            v0.x = fmaxf(v0.x, 0.f); v0.y = fmaxf(v0.y, 0.f);
            v1.x = fmaxf(v1.x, 0.f); v1.y = fmaxf(v1.y, 0.f);
            v2.x = fmaxf(v2.x, 0.f); v2.y = fmaxf(v2.y, 0.f);
            v3.x = fmaxf(v3.x, 0.f); v3.y = fmaxf(v3.y, 0.f);
        }
        a0 = fmaf(w0, v0.x, a0); a1 = fmaf(w0, v0.y, a1);
        b0 = fmaf(w1, v1.x, b0); b1 = fmaf(w1, v1.y, b1);
        c0 = fmaf(w2, v2.x, c0); c1 = fmaf(w2, v2.y, c1);
        d0 = fmaf(w3, v3.x, d0); d1 = fmaf(w3, v3.y, d1);
    }
    for (; e < e1; ++e) {
        int s = esrc[e];
        float w = ns[s];
        float2 v = *reinterpret_cast<const float2*>(xin + (size_t)s * 128 + lane * 2);
        if (RELU) { v.x = fmaxf(v.x, 0.f); v.y = fmaxf(v.y, 0.f); }
        a0 = fmaf(w, v.x, a0); a1 = fmaf(w, v.y, a1);
    }
    float nr = t.nd[wave];
    float r0 = ((a0 + b0) + (c0 + d0)) * nr;
    float r1 = ((a1 + b1) + (c1 + d1)) * nr;
    // split-bf16: hi = rn(v), lo = rn(v - hi)
    unsigned u0 = __float_as_uint(r0);
    unsigned h0b = (u0 + 0x7fffu + ((u0 >> 16) & 1u)) & 0xffff0000u;
    unsigned ul0 = __float_as_uint(r0 - __uint_as_float(h0b));
    unsigned u1 = __float_as_uint(r1);
    unsigned h1b = (u1 + 0x7fffu + ((u1 >> 16) & 1u)) & 0xffff0000u;
    unsigned ul1 = __float_as_uint(r1 - __uint_as_float(h1b));
    ushort2 hv, lv;
    hv.x = (unsigned short)(h0b >> 16);
    hv.y = (unsigned short)(h1b >> 16);
    lv.x = (unsigned short)((ul0 + 0x7fffu + ((ul0 >> 16) & 1u)) >> 16);
    lv.y = (unsigned short)((ul1 + 0x7fffu + ((ul1 >> 16) & 1u)) >> 16);
    *reinterpret_cast<ushort2*>(t.Ah + (size_t)wave * 128 + lane * 2) = hv;
    *reinterpret_cast<ushort2*>(t.Al + (size_t)wave * 128 + lane * 2) = lv;
}

// ---------------- MFMA GEMM: H (=|+=) sum_s A_s @ W_s + bias ----------------
// A planes: [NS][NN][128] bf16 (hi,lo). W planes: chunk-major [4][128][32].
// Block 256 thr = 4 waves; block tile 64 rows x 128 cols; wave = 32-col slice,
// 4 row-tiles x 2 col-tiles of 16x16. 3-pass split product per k-chunk.
template <int NS, int STORE>
__global__ __launch_bounds__(256) void k_gemm_mfma(
    const unsigned short* __restrict__ Ah, const unsigned short* __restrict__ Al,
    const unsigned short* __restrict__ wha, const unsigned short* __restrict__ wla,
    const unsigned short* __restrict__ whb, const unsigned short* __restrict__ wlb,
    const float* __restrict__ ba, const float* __restrict__ bb,
    float* __restrict__ H) {
    int tid = threadIdx.x;
    int w = tid >> 6, lane = tid & 63;
    int row0 = blockIdx.x * 64;
    int colbase = w * 32;
    int r16 = lane & 15;
    int koff = (lane >> 4) * 8;   // k element offset within 32-chunk

    f32x4 acc[4][2];
#pragma unroll
    for (int rt = 0; rt < 4; ++rt)
#pragma unroll
        for (int nt = 0; nt < 2; ++nt)
            acc[rt][nt] = f32x4{0.f, 0.f, 0.f, 0.f};

#pragma unroll
    for (int s = 0; s < NS; ++s) {
        const unsigned short* A_h = Ah + (size_t)s * NN * 128;
        const unsigned short* A_l = Al + (size_t)s * NN * 128;
        const unsigned short* w_h = (s == 0) ? wha : whb;
        const unsigned short* w_l = (s == 0) ? wla : wlb;
#pragma unroll
        for (int c = 0; c < 4; ++c) {
            int kbase = c * 32 + koff;
            bf16x8 ah[4], al[4], bh[2], bl[2];
#pragma unroll
            for (int rt = 0; rt < 4; ++rt) {
                int rr = rt * 16 + r16;
                // OOB rows: clamp to row 0 (results discarded by epilogue guard)
                int rc = (row0 + rr < NN) ? rr : 0;
                const unsigned short* ap = A_h + ((size_t)(row0 + rc)) * 128 + kbase;
                ah[rt] = *reinterpret_cast<const bf16x8*>(ap);
                al[rt] = *reinterpret_cast<const bf16x8*>(
                    A_l + ((size_t)(row0 + rc)) * 128 + kbase);
            }
#pragma unroll
            for (int nt = 0; nt < 2; ++nt) {
                int col = colbase + nt * 16 + r16;
                size_t widx = ((size_t)c * 128 + col) * 32 + koff;
                bh[nt] = *reinterpret_cast<const bf16x8*>(w_h + widx);
                bl[nt] = *reinterpret_cast<const bf16x8*>(w_l + widx);
            }
#pragma unroll
            for (int rt = 0; rt < 4; ++rt)
#pragma unroll
                for (int nt = 0; nt < 2; ++nt) {
                    acc[rt][nt] = MFMA16(ah[rt], bh[nt], acc[rt][nt]);
                    acc[rt][nt] = MFMA16(ah[rt], bl[nt], acc[rt][nt]);
                    acc[rt][nt] = MFMA16(al[rt], bh[nt], acc[rt][nt]);
                }
        }
    }

    // epilogue: D row = (lane>>4)*4 + j, col = lane&15 (per 16x16 tile)
    int orow = (lane >> 4) * 4;
#pragma unroll
    for (int nt = 0; nt < 2; ++nt) {
        int col = colbase + nt * 16 + r16;
        float bias = ba[col];
        if (NS == 2) bias += bb[col];
#pragma unroll
        for (int rt = 0; rt < 4; ++rt) {
#pragma unroll
            for (int j = 0; j < 4; ++j) {
                int grow = row0 + rt * 16 + orow + j;
                if (grow < NN) {
                    float* hp = H + (size_t)grow * 128 + col;
                    float v = acc[rt][nt][j] + bias;
                    if (!STORE) v += *hp;
                    *hp = v;
                }
            }
        }
    }
}

// ---------------- classifier: out = relu(H) @ Wc + bc -----------------------
__global__ __launch_bounds__(256) void k_classifier(const float* __restrict__ H,
                                                    const float* __restrict__ Wc,
                                                    const float* __restrict__ bc,
                                                    float* __restrict__ out) {
    __shared__ float sW[128 * 16];
    __shared__ float sb[16];
    int tid = threadIdx.x;
#pragma unroll
    for (int i = tid; i < 2048; i += 256) sW[i] = Wc[i];
    if (tid < 16) sb[tid] = bc[tid];
    __syncthreads();
    int node = blockIdx.x * 64 + (tid >> 2);
    if (node >= 3 * NN) return;
    int cg = (tid & 3) << 2;
    const float* h = H + (size_t)node * 128;
    float acc0 = 0.f, acc1 = 0.f, acc2 = 0.f, acc3 = 0.f;
#pragma unroll 4
    for (int k0 = 0; k0 < 128; k0 += 4) {
        float4 a4 = *reinterpret_cast<const float4*>(h + k0);
        float a;
        a = fmaxf(a4.x, 0.f);
        { float4 wv = *reinterpret_cast<const float4*>(&sW[(k0 + 0) * 16 + cg]);
          acc0 = fmaf(a, wv.x, acc0); acc1 = fmaf(a, wv.y, acc1);
          acc2 = fmaf(a, wv.z, acc2); acc3 = fmaf(a, wv.w, acc3); }
        a = fmaxf(a4.y, 0.f);
        { float4 wv = *reinterpret_cast<const float4*>(&sW[(k0 + 1) * 16 + cg]);
          acc0 = fmaf(a, wv.x, acc0); acc1 = fmaf(a, wv.y, acc1);
          acc2 = fmaf(a, wv.z, acc2); acc3 = fmaf(a, wv.w, acc3); }
        a = fmaxf(a4.z, 0.f);
        { float4 wv = *reinterpret_cast<const float4*>(&sW[(k0 + 2) * 16 + cg]);
          acc0 = fmaf(a, wv.x, acc0); acc1 = fmaf(a, wv.y, acc1);
          acc2 = fmaf(a, wv.z, acc2); acc3 = fmaf(a, wv.w, acc3); }
        a = fmaxf(a4.w, 0.f);
        { float4 wv = *reinterpret_cast<const float4*>(&sW[(k0 + 3) * 16 + cg]);
          acc0 = fmaf(a, wv.x, acc0); acc1 = fmaf(a, wv.y, acc1);
          acc2 = fmaf(a, wv.z, acc2); acc3 = fmaf(a, wv.w, acc3); }
    }
    float4 o = make_float4(acc0 + sb[cg], acc1 + sb[cg + 1],
                           acc2 + sb[cg + 2], acc3 + sb[cg + 3]);
    *reinterpret_cast<float4*>(out + (size_t)node * 16 + cg) = o;
}

// ---------------------------------------------------------------------------
extern "C" void kernel_launch(void* const* d_in, const int* in_sizes, int n_in,
                              void* d_out, int out_size, void* d_ws, size_t ws_size,
                              hipStream_t stream) {
    const float* x0 = (const float*)d_in[0];
    const float* x1 = (const float*)d_in[1];
    const float* x2 = (const float*)d_in[2];
    const float* W1 = (const float*)d_in[3];
    const float* b1 = (const float*)d_in[4];
    const float* W2 = (const float*)d_in[5];
    const float* b2 = (const float*)d_in[6];
    const float* Wc = (const float*)d_in[7];
    const float* bc = (const float*)d_in[8];
    const int* edges = (const int*)d_in[9];
    const float* x[3] = {x0, x1, x2};

    const int REL_S[9] = {0, 1, 1, 0, 2, 2, 0, 2, 1};

    // ---- workspace carve-up with overlays (~226 MB peak) ----
    char* p = (char*)d_ws;
    auto alloc = [&](size_t bytes) -> void* {
        void* r = (void*)p;
        p += (bytes + 255) & ~(size_t)255;
        return r;
    };
    float* h2 = (float*)alloc((size_t)3 * NN * 128 * sizeof(float));  // 76.8 MB
    unsigned* hist = (unsigned*)h2;    // alias: hist dead after k_sums
    float* h1 = (float*)alloc((size_t)3 * NN * 128 * sizeof(float));  // 76.8 MB
    int* cur = (int*)h1;               // alias: cur dead after k_fill
    int* deg_d = (int*)(h1 + 9 * NN);  // alias: deg_d dead after k_offsets
    unsigned short* Ah = (unsigned short*)alloc((size_t)2 * NN * 128 * 2);  // 25.6 MB
    unsigned short* Al = (unsigned short*)alloc((size_t)2 * NN * 128 * 2);  // 25.6 MB
    int* off = (int*)alloc((size_t)9 * (NN + 1) * sizeof(int));
    float* ns = (float*)alloc((size_t)9 * NN * sizeof(float));
    float* nd = (float*)alloc((size_t)9 * NN * sizeof(float));
    int* esrc = (int*)alloc((size_t)9 * EE * sizeof(int));            // 14.4 MB
    unsigned short* whi = (unsigned short*)alloc((size_t)2 * 9 * 128 * 128 * 2);
    unsigned short* wlo = (unsigned short*)alloc((size_t)2 * 9 * 128 * 128 * 2);
    unsigned short* Ah1 = Ah + (size_t)NN * 128;
    unsigned short* Al1 = Al + (size_t)NN * 128;

    // ---- CSR build + W prep (reused by both layers) ----
    k_hist<<<288, 256, 0, stream>>>(edges, hist);
    k_sums<<<(9 * (NN / 2) + 255) / 256, 256, 0, stream>>>(hist, ns, nd, deg_d);
    k_offsets<<<9, 256, 0, stream>>>(deg_d, off, cur);
    k_fill<<<(9 * EE + 255) / 256, 256, 0, stream>>>(edges, cur, esrc);
    k_wprep<<<(2 * 9 * 128 * 128 + 255) / 256, 256, 0, stream>>>(W1, W2, whi, wlo);

    const dim3 agg2_grid(12500, 2);
    const dim3 agg1_grid(12500, 1);
    const int gemm_blocks = (NN + 63) / 64;   // 782

    auto mk = [&](int r, const float* xin, unsigned short* ah, unsigned short* al) -> AggT {
        return AggT{xin, off + r * (NN + 1), esrc + (size_t)r * EE,
                    ns + r * NN, nd + r * NN, ah, al};
    };
    auto wp = [&](int layer, int r) { return (size_t)(layer * 9 + r) * 16384; };

    // ======== layer 1 (inputs x[], no relu) ========
    {
        const float* b = b1; float* h = h1; const int L = 0;
        k_agg2<0><<<agg2_grid, 256, 0, stream>>>(mk(2, x[REL_S[2]], Ah, Al),
                                                 mk(3, x[REL_S[3]], Ah1, Al1));
        k_gemm_mfma<2, 1><<<gemm_blocks, 256, 0, stream>>>(
            Ah, Al, whi + wp(L, 2), wlo + wp(L, 2), whi + wp(L, 3), wlo + wp(L, 3),
            b + 2 * 128, b + 3 * 128, h + (size_t)0 * NN * 128);
        k_agg2<0><<<agg2_grid, 256, 0, stream>>>(mk(5, x[REL_S[5]], Ah, Al),
                                                 mk(6, x[REL_S[6]], Ah1, Al1));
        k_gemm_mfma<2, 0><<<gemm_blocks, 256, 0, stream>>>(
            Ah, Al, whi + wp(L, 5), wlo + wp(L, 5), whi + wp(L, 6), wlo + wp(L, 6),
            b + 5 * 128, b + 6 * 128, h + (size_t)0 * NN * 128);
        k_agg2<0><<<agg2_grid, 256, 0, stream>>>(mk(4, x[REL_S[4]], Ah, Al),
                                                 mk(8, x[REL_S[8]], Ah1, Al1));
        k_gemm_mfma<2, 1><<<gemm_blocks, 256, 0, stream>>>(
            Ah, Al, whi + wp(L, 4), wlo + wp(L, 4), whi + wp(L, 8), wlo + wp(L, 8),
            b + 4 * 128, b + 8 * 128, h + (size_t)1 * NN * 128);
        k_agg2<0><<<agg2_grid, 256, 0, stream>>>(mk(0, x[REL_S[0]], Ah, Al),
                                                 mk(1, x[REL_S[1]], Ah1, Al1));
        k_gemm_mfma<2, 1><<<gemm_blocks, 256, 0, stream>>>(
            Ah, Al, whi + wp(L, 0), wlo + wp(L, 0), whi + wp(L, 1), wlo + wp(L, 1),
            b + 0 * 128, b + 1 * 128, h + (size_t)2 * NN * 128);
        k_agg2<0><<<agg1_grid, 256, 0, stream>>>(mk(7, x[REL_S[7]], Ah, Al),
                                                 mk(7, x[REL_S[7]], Ah, Al));
        k_gemm_mfma<1, 0><<<gemm_blocks, 256, 0, stream>>>(
            Ah, Al, whi + wp(L, 7), wlo + wp(L, 7), whi + wp(L, 7), wlo + wp(L, 7),
            b + 7 * 128, b + 7 * 128, h + (size_t)2 * NN * 128);
    }

    // ======== layer 2 (inputs relu(h1), folded into gather) ========
    {
        const float* b = b2; float* h = h2; const int L = 1;
        auto hin = [&](int r) { return h1 + (size_t)REL_S[r] * NN * 128; };
        k_agg2<1><<<agg2_grid, 256, 0, stream>>>(mk(2, hin(2), Ah, Al),
                                                 mk(3, hin(3), Ah1, Al1));
        k_gemm_mfma<2, 1><<<gemm_blocks, 256, 0, stream>>>(
            Ah, Al, whi + wp(L, 2), wlo + wp(L, 2), whi + wp(L, 3), wlo + wp(L, 3),
            b + 2 * 128, b + 3 * 128, h + (size_t)0 * NN * 128);
        k_agg2<1><<<agg2_grid, 256, 0, stream>>>(mk(5, hin(5), Ah, Al),
                                                 mk(6, hin(6), Ah1, Al1));
        k_gemm_mfma<2, 0><<<gemm_blocks, 256, 0, stream>>>(
            Ah, Al, whi + wp(L, 5), wlo + wp(L, 5), whi + wp(L, 6), wlo + wp(L, 6),
            b + 5 * 128, b + 6 * 128, h + (size_t)0 * NN * 128);
        k_agg2<1><<<agg2_grid, 256, 0, stream>>>(mk(4, hin(4), Ah, Al),
                                                 mk(8, hin(8), Ah1, Al1));
        k_gemm_mfma<2, 1><<<gemm_blocks, 256, 0, stream>>>(
            Ah, Al, whi + wp(L, 4), wlo + wp(L, 4), whi + wp(L, 8), wlo + wp(L, 8),
            b + 4 * 128, b + 8 * 128, h + (size_t)1 * NN * 128);
        k_agg2<1><<<agg2_grid, 256, 0, stream>>>(mk(0, hin(0), Ah, Al),
                                                 mk(1, hin(1), Ah1, Al1));
        k_gemm_mfma<2, 1><<<gemm_blocks, 256, 0, stream>>>(
            Ah, Al, whi + wp(L, 0), wlo + wp(L, 0), whi + wp(L, 1), wlo + wp(L, 1),
            b + 0 * 128, b + 1 * 128, h + (size_t)2 * NN * 128);
        k_agg2<1><<<agg1_grid, 256, 0, stream>>>(mk(7, hin(7), Ah, Al),
                                                 mk(7, hin(7), Ah, Al));
        k_gemm_mfma<1, 0><<<gemm_blocks, 256, 0, stream>>>(
            Ah, Al, whi + wp(L, 7), wlo + wp(L, 7), whi + wp(L, 7), wlo + wp(L, 7),
            b + 7 * 128, b + 7 * 128, h + (size_t)2 * NN * 128);
    }

    // ---- classifier: out = relu(h2) @ Wc + bc ----
    k_classifier<<<(3 * NN + 63) / 64, 256, 0, stream>>>(h2, Wc, bc, (float*)d_out);
}